// Round 1
// 2409.377 us; speedup vs baseline: 1.5330x; 1.5330x over previous
//
#include <hip/hip_runtime.h>

// ---------------------------------------------------------------------------
// FluxIPAttnProcessor — round 4: projections moved to MFMA via split-bf16.
// H=24, DH=128, TXT=512, IMG=1024, S=1536, HID=3072, IPD=1152, IPL=128
// fp32 GEMMs (MfmaUtil was 0) now run as error-compensated bf16 MFMA:
//   x = hi + lo (two bf16),  x*y ~= hi*hi + hi*lo + lo*hi   (err ~2^-17 rel)
// QKV triples fused into one col-segmented launch (shared A); both output
// projections fused into one row-segmented launch. flash_attn unchanged.
// Workspace layout unchanged: 19,660,800 floats = 78.6 MB.
// ---------------------------------------------------------------------------

#define HID 3072
#define DH 128
#define NH 24
#define TXT 512
#define SIMG 1024
#define SFULL 1536
#define IPL 128
#define IPD 1152
#define ATTN_SCALE 0.08838834764831845f  // 1/sqrt(128)

typedef __attribute__((ext_vector_type(8))) short bf16x8;
typedef __attribute__((ext_vector_type(4))) float f32x4;

// LDS row stride in shorts: 32 data + 8 pad = 80 B = 5*16 B (odd multiple of
// 16B) -> consecutive rows land on different 16B bank-slots; b128 reads/writes
// spread uniformly (2 lanes/slot = conflict-free).
#define LDST 40

// packed fp32->bf16 RNE: low 16 = bf16(a), high 16 = bf16(b)
__device__ __forceinline__ unsigned pkbf(float a, float b) {
  unsigned r;
  asm("v_cvt_pk_bf16_f32 %0, %1, %2" : "=v"(r) : "v"(a), "v"(b));
  return r;
}

// 8 floats -> 8 hi-bf16 (16B) + 8 lo-bf16 (16B). lo = x - float(hi), exact.
__device__ __forceinline__ void cvt_hi_lo(float4 fa, float4 fb, uint4* hi, uint4* lo) {
  unsigned h0 = pkbf(fa.x, fa.y), h1 = pkbf(fa.z, fa.w);
  unsigned h2 = pkbf(fb.x, fb.y), h3 = pkbf(fb.z, fb.w);
  float r0 = fa.x - __uint_as_float(h0 << 16);
  float r1 = fa.y - __uint_as_float(h0 & 0xffff0000u);
  float r2 = fa.z - __uint_as_float(h1 << 16);
  float r3 = fa.w - __uint_as_float(h1 & 0xffff0000u);
  float r4 = fb.x - __uint_as_float(h2 << 16);
  float r5 = fb.y - __uint_as_float(h2 & 0xffff0000u);
  float r6 = fb.z - __uint_as_float(h3 << 16);
  float r7 = fb.w - __uint_as_float(h3 & 0xffff0000u);
  *hi = make_uint4(h0, h1, h2, h3);
  *lo = make_uint4(pkbf(r0, r1), pkbf(r2, r3), pkbf(r4, r5), pkbf(r6, r7));
}

// ---------------------------------------------------------------------------
// 128x128 tile GEMM core: C[128,128] = A[128,K] @ W[128,K]^T + bias.
// 256 threads = 4 waves in 2x2; each wave owns 64x64 = 4x4 frags of 16x16.
// mfma_f32_16x16x32_bf16, fragment mapping per learn_hip m89/m92 (verified):
//   a-frag lane l: A[row = l&15][k = (l>>4)*8 + i], 8 contiguous shorts
//   b-frag lane l: W[col = l&15][k = (l>>4)*8 + i]  (B = W^T)
//   C/D   lane l: col = l&15, row = (l>>4)*4 + j
// K % 32 == 0 (3072, 1152 both OK). M, N multiples of 128 at call sites.
// ---------------------------------------------------------------------------
__device__ __forceinline__ void gemm128_core(
    const float* __restrict__ A, const float* __restrict__ W,
    const float* __restrict__ bias, float* __restrict__ C, int K, int ldC) {
  __shared__ short Ah[128 * LDST], Al[128 * LDST];
  __shared__ short Wh[128 * LDST], Wl[128 * LDST];
  const int tid = threadIdx.x;
  const int srow = tid >> 1;            // staging row 0..127 (2 thr/row)
  const int skb = (tid & 1) * 16;       // staging k base: 0 or 16
  const int sidx = srow * LDST + skb;
  const int lane = tid & 63, w = tid >> 6;
  const int wm = (w >> 1) * 64, wn = (w & 1) * 64;
  const int fr = lane & 15, kg = lane >> 4;
  const int aoff = (wm + fr) * LDST + kg * 8;
  const int boff = (wn + fr) * LDST + kg * 8;
  const float* ap = A + (size_t)srow * K + skb;
  const float* wp = W + (size_t)srow * K + skb;

  f32x4 acc[4][4];
#pragma unroll
  for (int i = 0; i < 4; ++i)
#pragma unroll
    for (int j = 0; j < 4; ++j) acc[i][j] = (f32x4){0.f, 0.f, 0.f, 0.f};

  for (int k0 = 0; k0 < K; k0 += 32) {
    // ---- stage: global fp32 -> split hi/lo bf16 -> LDS
    float4 a0 = *(const float4*)(ap + k0);
    float4 a1 = *(const float4*)(ap + k0 + 4);
    float4 a2 = *(const float4*)(ap + k0 + 8);
    float4 a3 = *(const float4*)(ap + k0 + 12);
    float4 b0 = *(const float4*)(wp + k0);
    float4 b1 = *(const float4*)(wp + k0 + 4);
    float4 b2 = *(const float4*)(wp + k0 + 8);
    float4 b3 = *(const float4*)(wp + k0 + 12);
    uint4 h, l;
    cvt_hi_lo(a0, a1, &h, &l);
    *(uint4*)&Ah[sidx] = h;     *(uint4*)&Al[sidx] = l;
    cvt_hi_lo(a2, a3, &h, &l);
    *(uint4*)&Ah[sidx + 8] = h; *(uint4*)&Al[sidx + 8] = l;
    cvt_hi_lo(b0, b1, &h, &l);
    *(uint4*)&Wh[sidx] = h;     *(uint4*)&Wl[sidx] = l;
    cvt_hi_lo(b2, b3, &h, &l);
    *(uint4*)&Wh[sidx + 8] = h; *(uint4*)&Wl[sidx + 8] = l;
    __syncthreads();
    // ---- fragments (ds_read_b128 each)
    bf16x8 fah[4], fal[4], fbh[4], fbl[4];
#pragma unroll
    for (int f = 0; f < 4; ++f) {
      fah[f] = *(const bf16x8*)&Ah[aoff + f * 16 * LDST];
      fal[f] = *(const bf16x8*)&Al[aoff + f * 16 * LDST];
      fbh[f] = *(const bf16x8*)&Wh[boff + f * 16 * LDST];
      fbl[f] = *(const bf16x8*)&Wl[boff + f * 16 * LDST];
    }
    // ---- 48 MFMAs: hi*hi + lo*hi + hi*lo (lo*lo dropped, ~2^-17 rel)
#pragma unroll
    for (int fm = 0; fm < 4; ++fm)
#pragma unroll
      for (int fn = 0; fn < 4; ++fn) {
        acc[fm][fn] = __builtin_amdgcn_mfma_f32_16x16x32_bf16(fah[fm], fbh[fn], acc[fm][fn], 0, 0, 0);
        acc[fm][fn] = __builtin_amdgcn_mfma_f32_16x16x32_bf16(fal[fm], fbh[fn], acc[fm][fn], 0, 0, 0);
        acc[fm][fn] = __builtin_amdgcn_mfma_f32_16x16x32_bf16(fah[fm], fbl[fn], acc[fm][fn], 0, 0, 0);
      }
    __syncthreads();
  }
  // ---- epilogue: C/D layout col=lane&15, row=(lane>>4)*4+j (m89-verified)
  const int r4 = kg * 4;
#pragma unroll
  for (int fn = 0; fn < 4; ++fn) {
    float bb = bias[wn + fn * 16 + fr];
#pragma unroll
    for (int fm = 0; fm < 4; ++fm) {
      f32x4 v = acc[fm][fn];
#pragma unroll
      for (int j = 0; j < 4; ++j)
        C[(size_t)(wm + fm * 16 + r4 + j) * ldC + (wn + fn * 16 + fr)] = v[j] + bb;
    }
  }
}

// Col-segmented fused GEMM: up to 3 weight/bias/output sets sharing one A.
// Each segment is N=3072 wide = 24 blocks of 128. seg is block-uniform.
struct Seg3 {
  const float *W0, *W1, *W2;
  const float *b0, *b1, *b2;
  float *C0, *C1, *C2;
};

__global__ __launch_bounds__(256) void gemm_seg3(const float* __restrict__ A, Seg3 s, int K) {
  const int seg = blockIdx.x / 24;
  const int n0 = (blockIdx.x % 24) * 128;
  const int m0 = blockIdx.y * 128;
  const float* W = seg == 0 ? s.W0 : (seg == 1 ? s.W1 : s.W2);
  const float* b = seg == 0 ? s.b0 : (seg == 1 ? s.b1 : s.b2);
  float* C = seg == 0 ? s.C0 : (seg == 1 ? s.C1 : s.C2);
  gemm128_core(A + (size_t)m0 * K, W + (size_t)n0 * K, b + n0,
               C + (size_t)m0 * HID + n0, K, HID);
}

// Row-segmented fused output projection: rows < TXT -> enc set, else img set.
__global__ __launch_bounds__(256) void gemm_out2(
    const float* __restrict__ A,
    const float* __restrict__ We, const float* __restrict__ be, float* __restrict__ Ce,
    const float* __restrict__ Wi, const float* __restrict__ bi, float* __restrict__ Ci,
    int K) {
  const int m0 = blockIdx.y * 128;
  const int n0 = blockIdx.x * 128;
  const float* W; const float* b; float* C; int cr;
  if (m0 < TXT) { W = We; b = be; C = Ce; cr = m0; }
  else          { W = Wi; b = bi; C = Ci; cr = m0 - TXT; }
  gemm128_core(A + (size_t)m0 * K, W + (size_t)n0 * K, b + n0,
               C + (size_t)cr * HID + n0, K, HID);
}

// ---- block-of-128 reductions (tree in LDS) --------------------------------
__device__ __forceinline__ float blk_sum128(float v, float* red) {
  int d = threadIdx.x;
  red[d] = v; __syncthreads();
  if (d < 64) red[d] += red[d + 64]; __syncthreads();
  if (d < 32) red[d] += red[d + 32]; __syncthreads();
  if (d < 16) red[d] += red[d + 16]; __syncthreads();
  if (d < 8)  red[d] += red[d + 8];  __syncthreads();
  if (d < 4)  red[d] += red[d + 4];  __syncthreads();
  if (d < 2)  red[d] += red[d + 2];  __syncthreads();
  if (d < 1)  red[d] += red[d + 1];  __syncthreads();
  float r = red[0]; __syncthreads();
  return r;
}
__device__ __forceinline__ float blk_max128(float v, float* red) {
  int d = threadIdx.x;
  red[d] = v; __syncthreads();
  if (d < 64) red[d] = fmaxf(red[d], red[d + 64]); __syncthreads();
  if (d < 32) red[d] = fmaxf(red[d], red[d + 32]); __syncthreads();
  if (d < 16) red[d] = fmaxf(red[d], red[d + 16]); __syncthreads();
  if (d < 8)  red[d] = fmaxf(red[d], red[d + 8]);  __syncthreads();
  if (d < 4)  red[d] = fmaxf(red[d], red[d + 4]);  __syncthreads();
  if (d < 2)  red[d] = fmaxf(red[d], red[d + 2]);  __syncthreads();
  if (d < 1)  red[d] = fmaxf(red[d], red[d + 1]);  __syncthreads();
  float r = red[0]; __syncthreads();
  return r;
}

// ---------------------------------------------------------------------------
// Reorder (L,3072)->(H,L,128) with optional per-head RMS norm (for IP K/V).
// grid (L, H), block 128
// ---------------------------------------------------------------------------
__global__ __launch_bounds__(128) void ip_norm_reorder(
    const float* __restrict__ src, const float* __restrict__ w,
    float* __restrict__ dst, int do_norm) {
  __shared__ float red[128];
  const int t = blockIdx.x, h = blockIdx.y, d = threadIdx.x;
  float v = src[(size_t)t * HID + h * DH + d];
  if (do_norm) {
    float ss = blk_sum128(v * v, red);
    v = v * rsqrtf(ss * (1.0f / DH) + 1e-6f) * w[d];
  }
  dst[((size_t)h * IPL + t) * DH + d] = v;
}

// ---------------------------------------------------------------------------
// IP attention: queries = rms(heads(Q)) with norm_ip_q_w; 128 keys.
// One block per (token, head); output pre-multiplied by bbox mask.
// grid (1024, 24), block 128.  Reads RAW Q (before in-place transform).
// ---------------------------------------------------------------------------
__global__ __launch_bounds__(128) void ip_attn(
    const float* __restrict__ Q, const float* __restrict__ KN,
    const float* __restrict__ VN, const float* __restrict__ qw,
    float* __restrict__ OUT) {
  const int t = blockIdx.x, h = blockIdx.y, d = threadIdx.x;
  const size_t qidx = (size_t)t * HID + h * DH + d;
  const size_t oidx = qidx;
  const int y = t >> 5, x = t & 31;
  if (!(y >= 8 && y < 24 && x >= 8 && x < 24)) { OUT[oidx] = 0.f; return; }
  __shared__ float qs[128], ps[128], red[128];
  float qv = Q[qidx];
  float ss = blk_sum128(qv * qv, red);
  qs[d] = qv * rsqrtf(ss * (1.0f / DH) + 1e-6f) * qw[d];
  __syncthreads();
  const float* krow = KN + ((size_t)h * IPL + d) * DH;  // thread d = key d
  float s = 0.f;
#pragma unroll 4
  for (int i = 0; i < 128; ++i) s += qs[i] * krow[i];
  s *= ATTN_SCALE;
  float mx = blk_max128(s, red);
  float p = __expf(s - mx);
  ps[d] = p;
  float lsum = blk_sum128(p, red);
  const float* vcol = VN + (size_t)h * IPL * DH + d;
  float o = 0.f;
#pragma unroll 4
  for (int j = 0; j < 128; ++j) o += ps[j] * vcol[(size_t)j * DH];
  OUT[oidx] = o / lsum;
}

// ---------------------------------------------------------------------------
// In-place per-head RMS + RoPE on the fused sequence (enc rows then img rows).
// grid (1536, 24), block 128. Row s<TXT lives in Xenc, else Ximg.
// ---------------------------------------------------------------------------
__global__ __launch_bounds__(128) void rms_rope_inplace(
    float* __restrict__ Xenc, float* __restrict__ Ximg,
    const float* __restrict__ w_enc, const float* __restrict__ w_img,
    const float* __restrict__ cosb, const float* __restrict__ sinb) {
  __shared__ float red[128];
  __shared__ float vs[128];
  const int s = blockIdx.x, h = blockIdx.y, d = threadIdx.x;
  float* p = ((s < TXT) ? Xenc + (size_t)s * HID : Ximg + (size_t)(s - TXT) * HID) + h * DH + d;
  float v = *p;
  float ss = blk_sum128(v * v, red);
  const float* w = (s < TXT) ? w_enc : w_img;
  v = v * rsqrtf(ss * (1.0f / DH) + 1e-6f) * w[d];
  vs[d] = v; __syncthreads();
  float other = (d & 1) ? vs[d - 1] : -vs[d + 1];
  *p = v * cosb[s * DH + d] + other * sinb[s * DH + d];
}

// ---------------------------------------------------------------------------
// Main attention, flash-style. 16 queries/block, 64-key tiles, online softmax.
// (unchanged this round — next target)
// ---------------------------------------------------------------------------
__global__ __launch_bounds__(128) void flash_attn(
    const float* __restrict__ Qenc, const float* __restrict__ Qimg,
    const float* __restrict__ Kenc, const float* __restrict__ Kimg,
    const float* __restrict__ Venc, const float* __restrict__ Vimg,
    float* __restrict__ AOUT) {
  __shared__ float Qt[16][132];
  __shared__ float Kt[64][132];
  __shared__ float P[16][68];
  __shared__ float mL[16], lL[16], aL[16];
  const int h = blockIdx.y;
  const int s0 = blockIdx.x * 16;
  const int tid = threadIdx.x;
  const int kg = tid & 15;   // QK: 4 keys kg*4..+3
  const int qg = tid >> 4;   // QK: 2 queries qg*2..+1
  const int d4 = tid & 31;   // PV: 4 dims d4*4..+3
  const int qh = tid >> 5;   // PV: 4 queries qh*4..+3

  const float* qsrc = (s0 < TXT) ? (Qenc + (size_t)s0 * HID)
                                 : (Qimg + (size_t)(s0 - TXT) * HID);
  for (int e = tid; e < 16 * 128; e += 128)
    Qt[e >> 7][e & 127] = qsrc[(size_t)(e >> 7) * HID + h * DH + (e & 127)];
  if (tid < 16) { mL[tid] = -1e30f; lL[tid] = 0.f; }
  float O[4][4] = {};

  for (int kt = 0; kt < SFULL / 64; ++kt) {
    __syncthreads();  // protect Kt/P from previous iteration's readers
    const int ks = kt * 64;
    const float* ksrc = (ks < TXT) ? (Kenc + (size_t)ks * HID)
                                   : (Kimg + (size_t)(ks - TXT) * HID);
    for (int e = tid; e < 64 * 128; e += 128)
      Kt[e >> 7][e & 127] = ksrc[(size_t)(e >> 7) * HID + h * DH + (e & 127)];
    __syncthreads();
    // ---- QK^T: scores for 4 keys x 2 queries per thread
    {
      float s[4][2] = {};
#pragma unroll 4
      for (int dd = 0; dd < 128; dd += 4) {
        float4 q0 = *(const float4*)&Qt[qg * 2 + 0][dd];
        float4 q1 = *(const float4*)&Qt[qg * 2 + 1][dd];
#pragma unroll
        for (int i = 0; i < 4; ++i) {
          float4 kv = *(const float4*)&Kt[kg * 4 + i][dd];
          s[i][0] += kv.x * q0.x + kv.y * q0.y + kv.z * q0.z + kv.w * q0.w;
          s[i][1] += kv.x * q1.x + kv.y * q1.y + kv.z * q1.z + kv.w * q1.w;
        }
      }
#pragma unroll
      for (int i = 0; i < 4; ++i) {
        P[qg * 2 + 0][kg * 4 + i] = s[i][0] * ATTN_SCALE;
        P[qg * 2 + 1][kg * 4 + i] = s[i][1] * ATTN_SCALE;
      }
    }
    __syncthreads();
    // ---- online softmax bookkeeping (serial per query, 16 lanes busy)
    if (tid < 16) {
      const int q = tid;
      float mt = mL[q];
#pragma unroll 8
      for (int k = 0; k < 64; ++k) mt = fmaxf(mt, P[q][k]);
      float a = __expf(mL[q] - mt);
      float lsum = 0.f;
#pragma unroll 8
      for (int k = 0; k < 64; ++k) { float p = __expf(P[q][k] - mt); P[q][k] = p; lsum += p; }
      lL[q] = lL[q] * a + lsum;
      mL[q] = mt; aL[q] = a;
    }
    __syncthreads();
    // ---- P@V: 4 queries x 4 dims per thread, V streamed from L2
    {
#pragma unroll
      for (int qq = 0; qq < 4; ++qq) {
        float a = aL[qh * 4 + qq];
        O[qq][0] *= a; O[qq][1] *= a; O[qq][2] *= a; O[qq][3] *= a;
      }
      const float* vsrc = (ks < TXT) ? (Venc + (size_t)ks * HID)
                                     : (Vimg + (size_t)(ks - TXT) * HID);
      const float* vbase = vsrc + h * DH + d4 * 4;
      for (int k4 = 0; k4 < 64; k4 += 4) {
        float4 v0 = *(const float4*)(vbase + (size_t)(k4 + 0) * HID);
        float4 v1 = *(const float4*)(vbase + (size_t)(k4 + 1) * HID);
        float4 v2 = *(const float4*)(vbase + (size_t)(k4 + 2) * HID);
        float4 v3 = *(const float4*)(vbase + (size_t)(k4 + 3) * HID);
#pragma unroll
        for (int qq = 0; qq < 4; ++qq) {
          float4 p = *(const float4*)&P[qh * 4 + qq][k4];
          O[qq][0] += p.x * v0.x + p.y * v1.x + p.z * v2.x + p.w * v3.x;
          O[qq][1] += p.x * v0.y + p.y * v1.y + p.z * v2.y + p.w * v3.y;
          O[qq][2] += p.x * v0.z + p.y * v1.z + p.z * v2.z + p.w * v3.z;
          O[qq][3] += p.x * v0.w + p.y * v1.w + p.z * v2.w + p.w * v3.w;
        }
      }
    }
  }
  __syncthreads();
#pragma unroll
  for (int qq = 0; qq < 4; ++qq) {
    const int q = qh * 4 + qq;
    const int s = s0 + q;
    float inv = 1.0f / lL[q];
    float4 o = make_float4(O[qq][0] * inv, O[qq][1] * inv, O[qq][2] * inv, O[qq][3] * inv);
    float* dst = AOUT + (size_t)s * HID + h * DH + d4 * 4;
    if (s >= TXT) {  // add pre-masked IP output already stored here
      o.x += dst[0]; o.y += dst[1]; o.z += dst[2]; o.w += dst[3];
    }
    *(float4*)dst = o;
  }
}

// ---------------------------------------------------------------------------
extern "C" void kernel_launch(void* const* d_in, const int* in_sizes, int n_in,
                              void* d_out, int out_size, void* d_ws, size_t ws_size,
                              hipStream_t stream) {
  const float* x    = (const float*)d_in[0];
  const float* enc  = (const float*)d_in[1];
  const float* ip   = (const float*)d_in[2];
  const float* cosb = (const float*)d_in[3];
  const float* sinb = (const float*)d_in[4];
  const float* Wq   = (const float*)d_in[5];
  const float* bq   = (const float*)d_in[6];
  const float* Wk   = (const float*)d_in[7];
  const float* bk   = (const float*)d_in[8];
  const float* Wv   = (const float*)d_in[9];
  const float* bv   = (const float*)d_in[10];
  const float* nqw  = (const float*)d_in[11];
  const float* nkw  = (const float*)d_in[12];
  const float* Wqa  = (const float*)d_in[13];
  const float* bqa  = (const float*)d_in[14];
  const float* Wka  = (const float*)d_in[15];
  const float* bka  = (const float*)d_in[16];
  const float* Wva  = (const float*)d_in[17];
  const float* bva  = (const float*)d_in[18];
  const float* naqw = (const float*)d_in[19];
  const float* nakw = (const float*)d_in[20];
  const float* Wo   = (const float*)d_in[21];
  const float* bo   = (const float*)d_in[22];
  const float* Wao  = (const float*)d_in[23];
  const float* bao  = (const float*)d_in[24];
  const float* Wkip = (const float*)d_in[25];
  const float* bkip = (const float*)d_in[26];
  const float* Wvip = (const float*)d_in[27];
  const float* bvip = (const float*)d_in[28];
  const float* nipq = (const float*)d_in[29];
  const float* nipk = (const float*)d_in[30];

  float* out_img = (float*)d_out;                       // (1024, 3072)
  float* out_enc = (float*)d_out + (size_t)SIMG * HID;  // (512, 3072)

  float* ws = (float*)d_ws;
  // workspace layout (float offsets), total 19,660,800 floats = 78.6 MB
  float* Q    = ws + 0;          // 1024x3072  (raw -> in-place rms+rope)
  float* K    = ws + 3145728;    // 1024x3072
  float* V    = ws + 6291456;    // 1024x3072
  float* EQ   = ws + 9437184;    // 512x3072
  float* EK   = ws + 11010048;   // 512x3072
  float* EV   = ws + 12582912;   // 512x3072
  float* KIPN = ws + 14155776;   // (24,128,128)
  float* VIPN = ws + 14548992;   // (24,128,128)
  float* AOUT = ws + 14942208;   // 1536x3072
  // aliases into AOUT (dead/overwritten later):
  float* KIP  = AOUT;                      // 128x3072, enc-row region
  float* VIP  = AOUT + 393216;             // 128x3072, enc-row region
  float* IPO  = AOUT + (size_t)TXT * HID;  // 1024x3072, img-row region

  dim3 blk256(256), blk128(128);

  // 1. QKV projections (img tokens) — one fused col-segmented MFMA launch
  gemm_seg3<<<dim3(72, 8), blk256, 0, stream>>>(
      x, Seg3{Wq, Wk, Wv, bq, bk, bv, Q, K, V}, HID);
  // 2. IP K/V projections (fused, 2 segments) + normalize/reorder + IP attn
  gemm_seg3<<<dim3(48, 1), blk256, 0, stream>>>(
      ip, Seg3{Wkip, Wvip, Wvip, bkip, bvip, bvip, KIP, VIP, VIP}, IPD);
  ip_norm_reorder<<<dim3(IPL, NH), blk128, 0, stream>>>(KIP, nipk, KIPN, 1);
  ip_norm_reorder<<<dim3(IPL, NH), blk128, 0, stream>>>(VIP, nullptr, VIPN, 0);
  ip_attn<<<dim3(SIMG, NH), blk128, 0, stream>>>(Q, KIPN, VIPN, nipq, IPO);
  // 3. encoder QKV projections — fused
  gemm_seg3<<<dim3(72, 4), blk256, 0, stream>>>(
      enc, Seg3{Wqa, Wka, Wva, bqa, bka, bva, EQ, EK, EV}, HID);
  // 4. in-place RMS + RoPE on Q (enc+img) and K (enc+img); V needs none
  rms_rope_inplace<<<dim3(SFULL, NH), blk128, 0, stream>>>(EQ, Q, naqw, nqw, cosb, sinb);
  rms_rope_inplace<<<dim3(SFULL, NH), blk128, 0, stream>>>(EK, K, nakw, nkw, cosb, sinb);
  // 5. main attention; adds IP output in-place on img rows
  flash_attn<<<dim3(SFULL / 16, NH), blk128, 0, stream>>>(EQ, Q, EK, K, EV, V, AOUT);
  // 6. fused output projections (row-segmented: enc rows -> Wao, img -> Wo)
  gemm_out2<<<dim3(24, 12), blk256, 0, stream>>>(
      AOUT, Wao, bao, out_enc, Wo, bo, out_img, HID);
}

// Round 2
// 1579.128 us; speedup vs baseline: 2.3390x; 1.5258x over previous
//
#include <hip/hip_runtime.h>

// ---------------------------------------------------------------------------
// FluxIPAttnProcessor — round 5: flash attention moved to MFMA (split-bf16).
// H=24, DH=128, TXT=512, IMG=1024, S=1536, HID=3072, IPD=1152, IPL=128
// Pre-passes pack Q/K as in-place hi|lo bf16 rows (RMS+RoPE fused, Q
// pre-scaled by 1/sqrt(128)); V is converted+transposed per head to
// VT[h][d][k] hi/lo. flash_mfma: 4 waves, QBLK=64, KVB=32, XOR-swizzled
// K LDS, wave-parallel softmax in regs, P through per-wave LDS as hi/lo,
// stage-ahead global loads. Workspace exactly 19,660,800 floats.
// ---------------------------------------------------------------------------

#define HID 3072
#define DH 128
#define NH 24
#define TXT 512
#define SIMG 1024
#define SFULL 1536
#define IPL 128
#define IPD 1152
#define ATTN_SCALE 0.08838834764831845f  // 1/sqrt(128)

typedef unsigned short u16;
typedef __attribute__((ext_vector_type(8))) short bf16x8;
typedef __attribute__((ext_vector_type(4))) float f32x4;

// GEMM LDS row stride in shorts: 32 data + 8 pad = 80 B (odd multiple of 16B)
#define LDST 40

// packed fp32->bf16 RNE: low 16 = bf16(a), high 16 = bf16(b)
__device__ __forceinline__ unsigned pkbf(float a, float b) {
  unsigned r;
  asm("v_cvt_pk_bf16_f32 %0, %1, %2" : "=v"(r) : "v"(a), "v"(b));
  return r;
}

// 8 floats -> 8 hi-bf16 (16B) + 8 lo-bf16 (16B). lo = x - float(hi), exact.
__device__ __forceinline__ void cvt_hi_lo(float4 fa, float4 fb, uint4* hi, uint4* lo) {
  unsigned h0 = pkbf(fa.x, fa.y), h1 = pkbf(fa.z, fa.w);
  unsigned h2 = pkbf(fb.x, fb.y), h3 = pkbf(fb.z, fb.w);
  float r0 = fa.x - __uint_as_float(h0 << 16);
  float r1 = fa.y - __uint_as_float(h0 & 0xffff0000u);
  float r2 = fa.z - __uint_as_float(h1 << 16);
  float r3 = fa.w - __uint_as_float(h1 & 0xffff0000u);
  float r4 = fb.x - __uint_as_float(h2 << 16);
  float r5 = fb.y - __uint_as_float(h2 & 0xffff0000u);
  float r6 = fb.z - __uint_as_float(h3 << 16);
  float r7 = fb.w - __uint_as_float(h3 & 0xffff0000u);
  *hi = make_uint4(h0, h1, h2, h3);
  *lo = make_uint4(pkbf(r0, r1), pkbf(r2, r3), pkbf(r4, r5), pkbf(r6, r7));
}

// ---------------------------------------------------------------------------
// 128x128 tile GEMM core (unchanged from round 4, harness-verified).
// ---------------------------------------------------------------------------
__device__ __forceinline__ void gemm128_core(
    const float* __restrict__ A, const float* __restrict__ W,
    const float* __restrict__ bias, float* __restrict__ C, int K, int ldC) {
  __shared__ short Ah[128 * LDST], Al[128 * LDST];
  __shared__ short Wh[128 * LDST], Wl[128 * LDST];
  const int tid = threadIdx.x;
  const int srow = tid >> 1;
  const int skb = (tid & 1) * 16;
  const int sidx = srow * LDST + skb;
  const int lane = tid & 63, w = tid >> 6;
  const int wm = (w >> 1) * 64, wn = (w & 1) * 64;
  const int fr = lane & 15, kg = lane >> 4;
  const int aoff = (wm + fr) * LDST + kg * 8;
  const int boff = (wn + fr) * LDST + kg * 8;
  const float* ap = A + (size_t)srow * K + skb;
  const float* wp = W + (size_t)srow * K + skb;

  f32x4 acc[4][4];
#pragma unroll
  for (int i = 0; i < 4; ++i)
#pragma unroll
    for (int j = 0; j < 4; ++j) acc[i][j] = (f32x4){0.f, 0.f, 0.f, 0.f};

  for (int k0 = 0; k0 < K; k0 += 32) {
    float4 a0 = *(const float4*)(ap + k0);
    float4 a1 = *(const float4*)(ap + k0 + 4);
    float4 a2 = *(const float4*)(ap + k0 + 8);
    float4 a3 = *(const float4*)(ap + k0 + 12);
    float4 b0 = *(const float4*)(wp + k0);
    float4 b1 = *(const float4*)(wp + k0 + 4);
    float4 b2 = *(const float4*)(wp + k0 + 8);
    float4 b3 = *(const float4*)(wp + k0 + 12);
    uint4 h, l;
    cvt_hi_lo(a0, a1, &h, &l);
    *(uint4*)&Ah[sidx] = h;     *(uint4*)&Al[sidx] = l;
    cvt_hi_lo(a2, a3, &h, &l);
    *(uint4*)&Ah[sidx + 8] = h; *(uint4*)&Al[sidx + 8] = l;
    cvt_hi_lo(b0, b1, &h, &l);
    *(uint4*)&Wh[sidx] = h;     *(uint4*)&Wl[sidx] = l;
    cvt_hi_lo(b2, b3, &h, &l);
    *(uint4*)&Wh[sidx + 8] = h; *(uint4*)&Wl[sidx + 8] = l;
    __syncthreads();
    bf16x8 fah[4], fal[4], fbh[4], fbl[4];
#pragma unroll
    for (int f = 0; f < 4; ++f) {
      fah[f] = *(const bf16x8*)&Ah[aoff + f * 16 * LDST];
      fal[f] = *(const bf16x8*)&Al[aoff + f * 16 * LDST];
      fbh[f] = *(const bf16x8*)&Wh[boff + f * 16 * LDST];
      fbl[f] = *(const bf16x8*)&Wl[boff + f * 16 * LDST];
    }
#pragma unroll
    for (int fm = 0; fm < 4; ++fm)
#pragma unroll
      for (int fn = 0; fn < 4; ++fn) {
        acc[fm][fn] = __builtin_amdgcn_mfma_f32_16x16x32_bf16(fah[fm], fbh[fn], acc[fm][fn], 0, 0, 0);
        acc[fm][fn] = __builtin_amdgcn_mfma_f32_16x16x32_bf16(fal[fm], fbh[fn], acc[fm][fn], 0, 0, 0);
        acc[fm][fn] = __builtin_amdgcn_mfma_f32_16x16x32_bf16(fah[fm], fbl[fn], acc[fm][fn], 0, 0, 0);
      }
    __syncthreads();
  }
  const int r4 = kg * 4;
#pragma unroll
  for (int fn = 0; fn < 4; ++fn) {
    float bb = bias[wn + fn * 16 + fr];
#pragma unroll
    for (int fm = 0; fm < 4; ++fm) {
      f32x4 v = acc[fm][fn];
#pragma unroll
      for (int j = 0; j < 4; ++j)
        C[(size_t)(wm + fm * 16 + r4 + j) * ldC + (wn + fn * 16 + fr)] = v[j] + bb;
    }
  }
}

struct Seg3 {
  const float *W0, *W1, *W2;
  const float *b0, *b1, *b2;
  float *C0, *C1, *C2;
};

__global__ __launch_bounds__(256) void gemm_seg3(const float* __restrict__ A, Seg3 s, int K) {
  const int seg = blockIdx.x / 24;
  const int n0 = (blockIdx.x % 24) * 128;
  const int m0 = blockIdx.y * 128;
  const float* W = seg == 0 ? s.W0 : (seg == 1 ? s.W1 : s.W2);
  const float* b = seg == 0 ? s.b0 : (seg == 1 ? s.b1 : s.b2);
  float* C = seg == 0 ? s.C0 : (seg == 1 ? s.C1 : s.C2);
  gemm128_core(A + (size_t)m0 * K, W + (size_t)n0 * K, b + n0,
               C + (size_t)m0 * HID + n0, K, HID);
}

__global__ __launch_bounds__(256) void gemm_out2(
    const float* __restrict__ A,
    const float* __restrict__ We, const float* __restrict__ be, float* __restrict__ Ce,
    const float* __restrict__ Wi, const float* __restrict__ bi, float* __restrict__ Ci,
    int K) {
  const int m0 = blockIdx.y * 128;
  const int n0 = blockIdx.x * 128;
  const float* W; const float* b; float* C; int cr;
  if (m0 < TXT) { W = We; b = be; C = Ce; cr = m0; }
  else          { W = Wi; b = bi; C = Ci; cr = m0 - TXT; }
  gemm128_core(A + (size_t)m0 * K, W + (size_t)n0 * K, b + n0,
               C + (size_t)cr * HID + n0, K, HID);
}

// ---- block-of-128 reductions (tree in LDS) --------------------------------
__device__ __forceinline__ float blk_sum128(float v, float* red) {
  int d = threadIdx.x;
  red[d] = v; __syncthreads();
  if (d < 64) red[d] += red[d + 64]; __syncthreads();
  if (d < 32) red[d] += red[d + 32]; __syncthreads();
  if (d < 16) red[d] += red[d + 16]; __syncthreads();
  if (d < 8)  red[d] += red[d + 8];  __syncthreads();
  if (d < 4)  red[d] += red[d + 4];  __syncthreads();
  if (d < 2)  red[d] += red[d + 2];  __syncthreads();
  if (d < 1)  red[d] += red[d + 1];  __syncthreads();
  float r = red[0]; __syncthreads();
  return r;
}
__device__ __forceinline__ float blk_max128(float v, float* red) {
  int d = threadIdx.x;
  red[d] = v; __syncthreads();
  if (d < 64) red[d] = fmaxf(red[d], red[d + 64]); __syncthreads();
  if (d < 32) red[d] = fmaxf(red[d], red[d + 32]); __syncthreads();
  if (d < 16) red[d] = fmaxf(red[d], red[d + 16]); __syncthreads();
  if (d < 8)  red[d] = fmaxf(red[d], red[d + 8]);  __syncthreads();
  if (d < 4)  red[d] = fmaxf(red[d], red[d + 4]);  __syncthreads();
  if (d < 2)  red[d] = fmaxf(red[d], red[d + 2]);  __syncthreads();
  if (d < 1)  red[d] = fmaxf(red[d], red[d + 1]);  __syncthreads();
  float r = red[0]; __syncthreads();
  return r;
}

// ---------------------------------------------------------------------------
// Reorder (L,3072)->(H,L,128) with optional per-head RMS norm (IP K/V).
// ---------------------------------------------------------------------------
__global__ __launch_bounds__(128) void ip_norm_reorder(
    const float* __restrict__ src, const float* __restrict__ w,
    float* __restrict__ dst, int do_norm) {
  __shared__ float red[128];
  const int t = blockIdx.x, h = blockIdx.y, d = threadIdx.x;
  float v = src[(size_t)t * HID + h * DH + d];
  if (do_norm) {
    float ss = blk_sum128(v * v, red);
    v = v * rsqrtf(ss * (1.0f / DH) + 1e-6f) * w[d];
  }
  dst[((size_t)h * IPL + t) * DH + d] = v;
}

// ---------------------------------------------------------------------------
// IP attention, bbox rows only (256 tokens). grid (256, 24), block 128.
// Reads RAW fp32 Q (before in-place rms+rope+convert). Output compact.
// ---------------------------------------------------------------------------
__global__ __launch_bounds__(128) void ip_attn(
    const float* __restrict__ Q, const float* __restrict__ KN,
    const float* __restrict__ VN, const float* __restrict__ qw,
    float* __restrict__ OUTc) {
  const int b = blockIdx.x, h = blockIdx.y, d = threadIdx.x;
  const int y = 8 + (b >> 4), x = 8 + (b & 15);
  const int t = y * 32 + x;
  __shared__ float qs[128], ps[128], red[128];
  float qv = Q[(size_t)t * HID + h * DH + d];
  float ss = blk_sum128(qv * qv, red);
  qs[d] = qv * rsqrtf(ss * (1.0f / DH) + 1e-6f) * qw[d];
  __syncthreads();
  const float* krow = KN + ((size_t)h * IPL + d) * DH;
  float s = 0.f;
#pragma unroll 4
  for (int i = 0; i < 128; ++i) s += qs[i] * krow[i];
  s *= ATTN_SCALE;
  float mx = blk_max128(s, red);
  float p = __expf(s - mx);
  ps[d] = p;
  float lsum = blk_sum128(p, red);
  const float* vcol = VN + (size_t)h * IPL * DH + d;
  float o = 0.f;
#pragma unroll 4
  for (int j = 0; j < 128; ++j) o += ps[j] * vcol[(size_t)j * DH];
  OUTc[(size_t)b * HID + h * DH + d] = o / lsum;
}

// ---------------------------------------------------------------------------
// Fused per-head RMS + RoPE + split-bf16 convert, IN PLACE.
// One block per row (768 thr = 24 heads x 32 thr x 4 elems). Packed output
// row: hi bf16 [0,3072) shorts | lo bf16 [3072,6144) shorts = same 12 KB.
// Q is pre-scaled by ATTN_SCALE (scale arg); K uses scale=1.
// ---------------------------------------------------------------------------
__global__ __launch_bounds__(768) void rmsrope_cvt(
    float* __restrict__ img, float* __restrict__ enc,
    const float* __restrict__ w_img, const float* __restrict__ w_enc,
    const float* __restrict__ cosb, const float* __restrict__ sinb, float scale) {
  const int s = blockIdx.x;
  const int t = threadIdx.x;
  float* row = (s < TXT) ? (enc + (size_t)s * HID) : (img + (size_t)(s - TXT) * HID);
  const float* w = (s < TXT) ? w_enc : w_img;
  const int dh = (t & 31) * 4;  // d within head
  float4 v = *(const float4*)(row + t * 4);
  float ss = v.x * v.x + v.y * v.y + v.z * v.z + v.w * v.w;
  ss += __shfl_xor(ss, 16); ss += __shfl_xor(ss, 8);
  ss += __shfl_xor(ss, 4);  ss += __shfl_xor(ss, 2); ss += __shfl_xor(ss, 1);
  float r = rsqrtf(ss * (1.0f / DH) + 1e-6f);
  float4 wv = *(const float4*)(w + dh);
  float n0 = v.x * r * wv.x, n1 = v.y * r * wv.y;
  float n2 = v.z * r * wv.z, n3 = v.w * r * wv.w;
  float4 cv = *(const float4*)(cosb + (size_t)s * DH + dh);
  float4 sv = *(const float4*)(sinb + (size_t)s * DH + dh);
  float o0 = (n0 * cv.x - n1 * sv.x) * scale;
  float o1 = (n1 * cv.y + n0 * sv.y) * scale;
  float o2 = (n2 * cv.z - n3 * sv.z) * scale;
  float o3 = (n3 * cv.w + n2 * sv.w) * scale;
  __syncthreads();  // all row reads complete before in-place overwrite
  unsigned h0 = pkbf(o0, o1), h1 = pkbf(o2, o3);
  float l0 = o0 - __uint_as_float(h0 << 16);
  float l1 = o1 - __uint_as_float(h0 & 0xffff0000u);
  float l2 = o2 - __uint_as_float(h1 << 16);
  float l3 = o3 - __uint_as_float(h1 & 0xffff0000u);
  unsigned lw0 = pkbf(l0, l1), lw1 = pkbf(l2, l3);
  unsigned* ur = (unsigned*)row;
  *(uint2*)(ur + t * 2) = make_uint2(h0, h1);
  *(uint2*)(ur + 1536 + t * 2) = make_uint2(lw0, lw1);
}

// ---------------------------------------------------------------------------
// V: fp32 -> per-head transposed bf16 hi/lo: VT[h][d][k], k enc-first order.
// grid (24 k-chunks of 64, 24 heads), block 256.
// ---------------------------------------------------------------------------
__global__ __launch_bounds__(256) void v_cvt_transpose(
    const float* __restrict__ Vimg, const float* __restrict__ Venc,
    u16* __restrict__ VTh, u16* __restrict__ VTl) {
  __shared__ float T[64][132];
  const int kc = blockIdx.x, h = blockIdx.y, tid = threadIdx.x;
  {
    const int r = tid >> 2, c = tid & 3;
    const int kk = kc * 64 + r;
    const float* src = ((kk < TXT) ? (Venc + (size_t)kk * HID)
                                   : (Vimg + (size_t)(kk - TXT) * HID)) + h * DH + c * 32;
#pragma unroll
    for (int i = 0; i < 8; ++i)
      *(float4*)&T[r][c * 32 + i * 4] = *(const float4*)(src + i * 4);
  }
  __syncthreads();
  const int d = tid >> 1, kh = tid & 1;
  unsigned hw[16], lw[16];
#pragma unroll
  for (int i = 0; i < 16; ++i) {
    float a = T[kh * 32 + i * 2 + 0][d];
    float b = T[kh * 32 + i * 2 + 1][d];
    unsigned hh = pkbf(a, b);
    float la = a - __uint_as_float(hh << 16);
    float lb = b - __uint_as_float(hh & 0xffff0000u);
    hw[i] = hh; lw[i] = pkbf(la, lb);
  }
  size_t base = ((size_t)h * DH + d) * SFULL + kc * 64 + kh * 32;
#pragma unroll
  for (int i = 0; i < 4; ++i) {
    *(uint4*)(VTh + base + i * 8) = make_uint4(hw[i*4], hw[i*4+1], hw[i*4+2], hw[i*4+3]);
    *(uint4*)(VTl + base + i * 8) = make_uint4(lw[i*4], lw[i*4+1], lw[i*4+2], lw[i*4+3]);
  }
}

// ---------------------------------------------------------------------------
// MFMA flash attention. grid (24, 24), 256 thr = 4 waves. QBLK=64 (16 q/wave),
// KVB=32. Split-bf16: S = Qh·Kh + Ql·Kh + Qh·Kl; O += Ph·Vh + Pl·Vh + Ph·Vl.
// Fragment maps identical to gemm128_core (verified): A lane: [row=l&15]
// [k=(l>>4)*8+i]; B lane: [col=l&15][k=(l>>4)*8+i]; C/D: col=l&15,
// row=(l>>4)*4+j. Softmax wave-parallel in regs (shfl over 16-lane groups).
// ---------------------------------------------------------------------------
#define KVB 32
#define NKT (SFULL / KVB)  // 48

__global__ __launch_bounds__(256) void flash_mfma(
    const float* __restrict__ Qimg, const float* __restrict__ Qenc,
    const float* __restrict__ Kimg, const float* __restrict__ Kenc,
    const u16* __restrict__ VTh, const u16* __restrict__ VTl,
    const float* __restrict__ IPOc, float* __restrict__ AOUT) {
  __shared__ __align__(16) u16 Klds[2][KVB * 128];   // [plane], XOR-swizzled rows
  __shared__ __align__(16) u16 Vlds[2][128 * 40];    // [plane][d*40+k], pad 80B
  __shared__ __align__(16) u16 Plds[4][2][16 * 40];  // [wave][plane][q*40+k]
  const int tid = threadIdx.x;
  const int lane = tid & 63, w = tid >> 6;
  const int h = blockIdx.y;
  const int q0 = blockIdx.x * 64;
  const int l15 = lane & 15, lg = lane >> 4;

  // ---- Q fragments in registers (4 k-steps x hi/lo), scaled already
  bf16x8 qf[4][2];
  {
    const int qrow = q0 + w * 16 + l15;
    const u16* rp = (qrow < TXT) ? (const u16*)(Qenc + (size_t)qrow * HID)
                                 : (const u16*)(Qimg + (size_t)(qrow - TXT) * HID);
#pragma unroll
    for (int ks = 0; ks < 4; ++ks) {
      qf[ks][0] = *(const bf16x8*)(rp + h * DH + ks * 32 + lg * 8);
      qf[ks][1] = *(const bf16x8*)(rp + 3072 + h * DH + ks * 32 + lg * 8);
    }
  }

  f32x4 O[8];
#pragma unroll
  for (int i = 0; i < 8; ++i) O[i] = (f32x4){0.f, 0.f, 0.f, 0.f};
  float mrun[4], lrun[4];
#pragma unroll
  for (int j = 0; j < 4; ++j) { mrun[j] = -1e30f; lrun[j] = 0.f; }

  uint4 kr[4], vr[4];
  // stage_load: fetch tile kt into regs (K: 32x128x2 planes; V: 128x32x2)
#define STAGE_LOAD(kt)                                                          \
  {                                                                             \
    _Pragma("unroll")                                                           \
    for (int it = 0; it < 4; ++it) {                                            \
      const int c = tid + it * 256;                                             \
      const int pl = c >> 9, rowk = (c >> 4) & 31, ch = c & 15;                 \
      const int kk = (kt) * KVB + rowk;                                         \
      const u16* rp = (kk < TXT) ? (const u16*)(Kenc + (size_t)kk * HID)        \
                                 : (const u16*)(Kimg + (size_t)(kk - TXT) * HID); \
      kr[it] = *(const uint4*)(rp + pl * 3072 + h * DH + ch * 8);               \
      const int dv = (c >> 2) & 127, cv = c & 3;                                \
      const u16* vp = (pl ? VTl : VTh) + ((size_t)h * DH + dv) * SFULL          \
                      + (kt) * KVB + cv * 8;                                    \
      vr[it] = *(const uint4*)vp;                                               \
    }                                                                           \
  }

  STAGE_LOAD(0)
  for (int kt = 0; kt < NKT; ++kt) {
    __syncthreads();  // all waves done reading previous tile's LDS
    // ---- write staged regs to LDS
#pragma unroll
    for (int it = 0; it < 4; ++it) {
      const int c = tid + it * 256;
      const int pl = c >> 9, rowk = (c >> 4) & 31, ch = c & 15;
      *(uint4*)((char*)&Klds[pl][0] + ((rowk * 256 + ch * 16) ^ ((rowk & 7) << 4))) = kr[it];
      const int dv = (c >> 2) & 127, cv = c & 3;
      *(uint4*)&Vlds[pl][dv * 40 + cv * 8] = vr[it];
    }
    if (kt + 1 < NKT) STAGE_LOAD(kt + 1)  // overlap next-tile loads w/ compute
    __syncthreads();

    // ---- QK^T: S strip 16q x 32k per wave
    f32x4 sA[2] = {(f32x4){0.f, 0.f, 0.f, 0.f}, (f32x4){0.f, 0.f, 0.f, 0.f}};
#pragma unroll
    for (int ks = 0; ks < 4; ++ks)
#pragma unroll
      for (int fn = 0; fn < 2; ++fn) {
        const int krow = fn * 16 + l15;
        const int off = (krow * 256 + ks * 64 + lg * 16) ^ ((krow & 7) << 4);
        bf16x8 kh = *(const bf16x8*)((const char*)&Klds[0][0] + off);
        bf16x8 kl = *(const bf16x8*)((const char*)&Klds[1][0] + off);
        sA[fn] = __builtin_amdgcn_mfma_f32_16x16x32_bf16(qf[ks][0], kh, sA[fn], 0, 0, 0);
        sA[fn] = __builtin_amdgcn_mfma_f32_16x16x32_bf16(qf[ks][1], kh, sA[fn], 0, 0, 0);
        sA[fn] = __builtin_amdgcn_mfma_f32_16x16x32_bf16(qf[ks][0], kl, sA[fn], 0, 0, 0);
      }

    // ---- online softmax, wave-parallel (rows q=lg*4+j, cols k across lanes)
#pragma unroll
    for (int j = 0; j < 4; ++j) {
      float v0 = sA[0][j], v1 = sA[1][j];
      float mx = fmaxf(v0, v1);
      mx = fmaxf(mx, __shfl_xor(mx, 1));
      mx = fmaxf(mx, __shfl_xor(mx, 2));
      mx = fmaxf(mx, __shfl_xor(mx, 4));
      mx = fmaxf(mx, __shfl_xor(mx, 8));
      float mnew = fmaxf(mrun[j], mx);
      float a = __expf(mrun[j] - mnew);
      mrun[j] = mnew;
      float p0 = __expf(v0 - mnew), p1 = __expf(v1 - mnew);
      float ts = p0 + p1;
      ts += __shfl_xor(ts, 1); ts += __shfl_xor(ts, 2);
      ts += __shfl_xor(ts, 4); ts += __shfl_xor(ts, 8);
      lrun[j] = lrun[j] * a + ts;
#pragma unroll
      for (int fn = 0; fn < 8; ++fn) O[fn][j] *= a;
      // P -> hi/lo bf16 into per-wave LDS strip [q][k]
      unsigned hp0 = pkbf(p0, 0.f), hp1 = pkbf(p1, 0.f);
      float lp0 = p0 - __uint_as_float(hp0 << 16);
      float lp1 = p1 - __uint_as_float(hp1 << 16);
      unsigned lo0 = pkbf(lp0, 0.f), lo1 = pkbf(lp1, 0.f);
      const int q = lg * 4 + j;
      Plds[w][0][q * 40 + l15]      = (u16)hp0;
      Plds[w][0][q * 40 + 16 + l15] = (u16)hp1;
      Plds[w][1][q * 40 + l15]      = (u16)lo0;
      Plds[w][1][q * 40 + 16 + l15] = (u16)lo1;
    }

    // ---- P @ V  (A = P strip, B = VT tile)
    bf16x8 pa0 = *(const bf16x8*)&Plds[w][0][l15 * 40 + lg * 8];
    bf16x8 pa1 = *(const bf16x8*)&Plds[w][1][l15 * 40 + lg * 8];
#pragma unroll
    for (int fn = 0; fn < 8; ++fn) {
      const int dd = fn * 16 + l15;
      bf16x8 vh = *(const bf16x8*)&Vlds[0][dd * 40 + lg * 8];
      bf16x8 vl = *(const bf16x8*)&Vlds[1][dd * 40 + lg * 8];
      O[fn] = __builtin_amdgcn_mfma_f32_16x16x32_bf16(pa0, vh, O[fn], 0, 0, 0);
      O[fn] = __builtin_amdgcn_mfma_f32_16x16x32_bf16(pa1, vh, O[fn], 0, 0, 0);
      O[fn] = __builtin_amdgcn_mfma_f32_16x16x32_bf16(pa0, vl, O[fn], 0, 0, 0);
    }
  }
#undef STAGE_LOAD

  // ---- epilogue: normalize, add compact IP output on bbox rows, store fp32
#pragma unroll
  for (int j = 0; j < 4; ++j) {
    const float inv = 1.0f / lrun[j];
    const int s = q0 + w * 16 + lg * 4 + j;
    float* orow = AOUT + (size_t)s * HID + h * DH;
    const float* iprow = nullptr;
    if (s >= TXT) {
      const int t2 = s - TXT, y = t2 >> 5, x = t2 & 31;
      if (y >= 8 && y < 24 && x >= 8 && x < 24)
        iprow = IPOc + (size_t)((y - 8) * 16 + (x - 8)) * HID + h * DH;
    }
#pragma unroll
    for (int fn = 0; fn < 8; ++fn) {
      float val = O[fn][j] * inv;
      const int dd = fn * 16 + l15;
      if (iprow) val += iprow[dd];
      orow[dd] = val;
    }
  }
}

// ---------------------------------------------------------------------------
extern "C" void kernel_launch(void* const* d_in, const int* in_sizes, int n_in,
                              void* d_out, int out_size, void* d_ws, size_t ws_size,
                              hipStream_t stream) {
  const float* x    = (const float*)d_in[0];
  const float* enc  = (const float*)d_in[1];
  const float* ip   = (const float*)d_in[2];
  const float* cosb = (const float*)d_in[3];
  const float* sinb = (const float*)d_in[4];
  const float* Wq   = (const float*)d_in[5];
  const float* bq   = (const float*)d_in[6];
  const float* Wk   = (const float*)d_in[7];
  const float* bk   = (const float*)d_in[8];
  const float* Wv   = (const float*)d_in[9];
  const float* bv   = (const float*)d_in[10];
  const float* nqw  = (const float*)d_in[11];
  const float* nkw  = (const float*)d_in[12];
  const float* Wqa  = (const float*)d_in[13];
  const float* bqa  = (const float*)d_in[14];
  const float* Wka  = (const float*)d_in[15];
  const float* bka  = (const float*)d_in[16];
  const float* Wva  = (const float*)d_in[17];
  const float* bva  = (const float*)d_in[18];
  const float* naqw = (const float*)d_in[19];
  const float* nakw = (const float*)d_in[20];
  const float* Wo   = (const float*)d_in[21];
  const float* bo   = (const float*)d_in[22];
  const float* Wao  = (const float*)d_in[23];
  const float* bao  = (const float*)d_in[24];
  const float* Wkip = (const float*)d_in[25];
  const float* bkip = (const float*)d_in[26];
  const float* Wvip = (const float*)d_in[27];
  const float* bvip = (const float*)d_in[28];
  const float* nipq = (const float*)d_in[29];
  const float* nipk = (const float*)d_in[30];

  float* out_img = (float*)d_out;                       // (1024, 3072)
  float* out_enc = (float*)d_out + (size_t)SIMG * HID;  // (512, 3072)

  float* ws = (float*)d_ws;
  // workspace layout (float offsets), total 19,660,800 floats = 78.6 MB
  float* Qi  = ws + 0;          // img Q fp32 -> packed hi|lo bf16 (1024 rows)
  float* Qe  = ws + 3145728;    // enc Q (512 rows)
  float* Ki  = ws + 4718592;    // img K
  float* Ke  = ws + 7864320;    // enc K
  float* Vi  = ws + 9437184;    // img V  }-> AOUT (1536 rows) after transpose
  float* Ve  = ws + 12582912;   // enc V  }
  float* VTr = ws + 14155776;   // VT region: 4,718,592 floats
  float* IPOc= ws + 18874368;   // compact IP out (256 x 3072)
  // temporaries inside the VT region (dead before v_cvt_transpose runs):
  float* KIP  = VTr;                 // 128x3072
  float* VIP  = VTr + 393216;        // 128x3072
  float* KIPN = VTr + 786432;        // (24,128,128)
  float* VIPN = VTr + 1179648;       // (24,128,128)
  u16* VTh = (u16*)VTr;              // (24,128,1536) hi
  u16* VTl = (u16*)(VTr + 2359296);  // (24,128,1536) lo
  float* AOUT = Vi;                  // rows: 0..511 enc, 512..1535 img

  dim3 blk256(256), blk128(128);

  // 1. QKV projections (img + enc), fused col-segmented MFMA launches
  gemm_seg3<<<dim3(72, 8), blk256, 0, stream>>>(
      x, Seg3{Wq, Wk, Wv, bq, bk, bv, Qi, Ki, Vi}, HID);
  gemm_seg3<<<dim3(72, 4), blk256, 0, stream>>>(
      enc, Seg3{Wqa, Wka, Wva, bqa, bka, bva, Qe, Ke, Ve}, HID);
  // 2. IP K/V projections + normalize/reorder + IP attention (raw fp32 Q)
  gemm_seg3<<<dim3(48, 1), blk256, 0, stream>>>(
      ip, Seg3{Wkip, Wvip, Wvip, bkip, bvip, bvip, KIP, VIP, VIP}, IPD);
  ip_norm_reorder<<<dim3(IPL, NH), blk128, 0, stream>>>(KIP, nipk, KIPN, 1);
  ip_norm_reorder<<<dim3(IPL, NH), blk128, 0, stream>>>(VIP, nullptr, VIPN, 0);
  ip_attn<<<dim3(256, NH), blk128, 0, stream>>>(Qi, KIPN, VIPN, nipq, IPOc);
  // 3. RMS+RoPE+split-bf16 convert in place (Q pre-scaled); V -> VT hi/lo
  rmsrope_cvt<<<dim3(SFULL), dim3(768), 0, stream>>>(Qi, Qe, nqw, naqw, cosb, sinb, ATTN_SCALE);
  rmsrope_cvt<<<dim3(SFULL), dim3(768), 0, stream>>>(Ki, Ke, nkw, nakw, cosb, sinb, 1.0f);
  v_cvt_transpose<<<dim3(24, NH), blk256, 0, stream>>>(Vi, Ve, VTh, VTl);
  // 4. MFMA flash attention (adds compact IP output on bbox rows)
  flash_mfma<<<dim3(24, NH), blk256, 0, stream>>>(Qi, Qe, Ki, Ke, VTh, VTl, IPOc, AOUT);
  // 5. fused output projections (row-segmented: enc rows -> Wao, img -> Wo)
  gemm_out2<<<dim3(24, 12), blk256, 0, stream>>>(
      AOUT, Wao, bao, out_enc, Wo, bo, out_img, HID);
}

// Round 3
// 1493.663 us; speedup vs baseline: 2.4729x; 1.0572x over previous
//
#include <hip/hip_runtime.h>

// ---------------------------------------------------------------------------
// FluxIPAttnProcessor — round 6: kill flash_mfma scratch spill + XCD swizzle.
// Round-5 post-mortem: WRITE_SIZE 745 MB ~= staged bytes/tile -> kr[]/vr[]
// stage-ahead regs spilled to scratch (VGPR_Count=100 ~= 512/5: compiler
// targeted 5 waves/EU while LDS caps at 3). Fix: __launch_bounds__(256,3)
// (VGPR cap ~168) + straight-line clamped prefetch. Plus XCD-bijective
// blockIdx swizzle (T1) on flash (3 heads/XCD -> K/V L2-resident) and on
// all GEMMs (m-fastest within XCD -> W-panels fetched once).
// ---------------------------------------------------------------------------

#define HID 3072
#define DH 128
#define NH 24
#define TXT 512
#define SIMG 1024
#define SFULL 1536
#define IPL 128
#define IPD 1152
#define ATTN_SCALE 0.08838834764831845f  // 1/sqrt(128)

typedef unsigned short u16;
typedef __attribute__((ext_vector_type(8))) short bf16x8;
typedef __attribute__((ext_vector_type(4))) float f32x4;

// GEMM LDS row stride in shorts: 32 data + 8 pad = 80 B (odd multiple of 16B)
#define LDST 40

// XCD-bijective block swizzle (requires nwg % 8 == 0; all our grids comply).
// Consecutive swizzled ids land on ONE XCD.
__device__ __forceinline__ int xcd_swz(int flat, int nwg) {
  return (flat & 7) * (nwg >> 3) + (flat >> 3);
}

// packed fp32->bf16 RNE: low 16 = bf16(a), high 16 = bf16(b)
__device__ __forceinline__ unsigned pkbf(float a, float b) {
  unsigned r;
  asm("v_cvt_pk_bf16_f32 %0, %1, %2" : "=v"(r) : "v"(a), "v"(b));
  return r;
}

// 8 floats -> 8 hi-bf16 (16B) + 8 lo-bf16 (16B). lo = x - float(hi), exact.
__device__ __forceinline__ void cvt_hi_lo(float4 fa, float4 fb, uint4* hi, uint4* lo) {
  unsigned h0 = pkbf(fa.x, fa.y), h1 = pkbf(fa.z, fa.w);
  unsigned h2 = pkbf(fb.x, fb.y), h3 = pkbf(fb.z, fb.w);
  float r0 = fa.x - __uint_as_float(h0 << 16);
  float r1 = fa.y - __uint_as_float(h0 & 0xffff0000u);
  float r2 = fa.z - __uint_as_float(h1 << 16);
  float r3 = fa.w - __uint_as_float(h1 & 0xffff0000u);
  float r4 = fb.x - __uint_as_float(h2 << 16);
  float r5 = fb.y - __uint_as_float(h2 & 0xffff0000u);
  float r6 = fb.z - __uint_as_float(h3 << 16);
  float r7 = fb.w - __uint_as_float(h3 & 0xffff0000u);
  *hi = make_uint4(h0, h1, h2, h3);
  *lo = make_uint4(pkbf(r0, r1), pkbf(r2, r3), pkbf(r4, r5), pkbf(r6, r7));
}

// ---------------------------------------------------------------------------
// 128x128 tile GEMM core (harness-verified rounds 4-5).
// ---------------------------------------------------------------------------
__device__ __forceinline__ void gemm128_core(
    const float* __restrict__ A, const float* __restrict__ W,
    const float* __restrict__ bias, float* __restrict__ C, int K, int ldC) {
  __shared__ short Ah[128 * LDST], Al[128 * LDST];
  __shared__ short Wh[128 * LDST], Wl[128 * LDST];
  const int tid = threadIdx.x;
  const int srow = tid >> 1;
  const int skb = (tid & 1) * 16;
  const int sidx = srow * LDST + skb;
  const int lane = tid & 63, w = tid >> 6;
  const int wm = (w >> 1) * 64, wn = (w & 1) * 64;
  const int fr = lane & 15, kg = lane >> 4;
  const int aoff = (wm + fr) * LDST + kg * 8;
  const int boff = (wn + fr) * LDST + kg * 8;
  const float* ap = A + (size_t)srow * K + skb;
  const float* wp = W + (size_t)srow * K + skb;

  f32x4 acc[4][4];
#pragma unroll
  for (int i = 0; i < 4; ++i)
#pragma unroll
    for (int j = 0; j < 4; ++j) acc[i][j] = (f32x4){0.f, 0.f, 0.f, 0.f};

  for (int k0 = 0; k0 < K; k0 += 32) {
    float4 a0 = *(const float4*)(ap + k0);
    float4 a1 = *(const float4*)(ap + k0 + 4);
    float4 a2 = *(const float4*)(ap + k0 + 8);
    float4 a3 = *(const float4*)(ap + k0 + 12);
    float4 b0 = *(const float4*)(wp + k0);
    float4 b1 = *(const float4*)(wp + k0 + 4);
    float4 b2 = *(const float4*)(wp + k0 + 8);
    float4 b3 = *(const float4*)(wp + k0 + 12);
    uint4 h, l;
    cvt_hi_lo(a0, a1, &h, &l);
    *(uint4*)&Ah[sidx] = h;     *(uint4*)&Al[sidx] = l;
    cvt_hi_lo(a2, a3, &h, &l);
    *(uint4*)&Ah[sidx + 8] = h; *(uint4*)&Al[sidx + 8] = l;
    cvt_hi_lo(b0, b1, &h, &l);
    *(uint4*)&Wh[sidx] = h;     *(uint4*)&Wl[sidx] = l;
    cvt_hi_lo(b2, b3, &h, &l);
    *(uint4*)&Wh[sidx + 8] = h; *(uint4*)&Wl[sidx + 8] = l;
    __syncthreads();
    bf16x8 fah[4], fal[4], fbh[4], fbl[4];
#pragma unroll
    for (int f = 0; f < 4; ++f) {
      fah[f] = *(const bf16x8*)&Ah[aoff + f * 16 * LDST];
      fal[f] = *(const bf16x8*)&Al[aoff + f * 16 * LDST];
      fbh[f] = *(const bf16x8*)&Wh[boff + f * 16 * LDST];
      fbl[f] = *(const bf16x8*)&Wl[boff + f * 16 * LDST];
    }
#pragma unroll
    for (int fm = 0; fm < 4; ++fm)
#pragma unroll
      for (int fn = 0; fn < 4; ++fn) {
        acc[fm][fn] = __builtin_amdgcn_mfma_f32_16x16x32_bf16(fah[fm], fbh[fn], acc[fm][fn], 0, 0, 0);
        acc[fm][fn] = __builtin_amdgcn_mfma_f32_16x16x32_bf16(fal[fm], fbh[fn], acc[fm][fn], 0, 0, 0);
        acc[fm][fn] = __builtin_amdgcn_mfma_f32_16x16x32_bf16(fah[fm], fbl[fn], acc[fm][fn], 0, 0, 0);
      }
    __syncthreads();
  }
  const int r4 = kg * 4;
#pragma unroll
  for (int fn = 0; fn < 4; ++fn) {
    float bb = bias[wn + fn * 16 + fr];
#pragma unroll
    for (int fm = 0; fm < 4; ++fm) {
      f32x4 v = acc[fm][fn];
#pragma unroll
      for (int j = 0; j < 4; ++j)
        C[(size_t)(wm + fm * 16 + r4 + j) * ldC + (wn + fn * 16 + fr)] = v[j] + bb;
    }
  }
}

struct Seg3 {
  const float *W0, *W1, *W2;
  const float *b0, *b1, *b2;
  float *C0, *C1, *C2;
};

__global__ __launch_bounds__(256) void gemm_seg3(const float* __restrict__ A, Seg3 s, int K) {
  // XCD swizzle, m-fastest within XCD -> each XCD owns a slice of W panels
  const int nwg = gridDim.x * gridDim.y;
  const int sw = xcd_swz(blockIdx.y * gridDim.x + blockIdx.x, nwg);
  const int by = sw % gridDim.y;        // m tile (fastest)
  const int bx = sw / gridDim.y;        // seg*24 + n tile
  const int seg = bx / 24;
  const int n0 = (bx % 24) * 128;
  const int m0 = by * 128;
  const float* W = seg == 0 ? s.W0 : (seg == 1 ? s.W1 : s.W2);
  const float* b = seg == 0 ? s.b0 : (seg == 1 ? s.b1 : s.b2);
  float* C = seg == 0 ? s.C0 : (seg == 1 ? s.C1 : s.C2);
  gemm128_core(A + (size_t)m0 * K, W + (size_t)n0 * K, b + n0,
               C + (size_t)m0 * HID + n0, K, HID);
}

__global__ __launch_bounds__(256) void gemm_out2(
    const float* __restrict__ A,
    const float* __restrict__ We, const float* __restrict__ be, float* __restrict__ Ce,
    const float* __restrict__ Wi, const float* __restrict__ bi, float* __restrict__ Ci,
    int K) {
  const int nwg = gridDim.x * gridDim.y;
  const int sw = xcd_swz(blockIdx.y * gridDim.x + blockIdx.x, nwg);
  const int by = sw % gridDim.y;        // m tile (fastest)
  const int bx = sw / gridDim.y;        // n tile
  const int m0 = by * 128;
  const int n0 = bx * 128;
  const float* W; const float* b; float* C; int cr;
  if (m0 < TXT) { W = We; b = be; C = Ce; cr = m0; }
  else          { W = Wi; b = bi; C = Ci; cr = m0 - TXT; }
  gemm128_core(A + (size_t)m0 * K, W + (size_t)n0 * K, b + n0,
               C + (size_t)cr * HID + n0, K, HID);
}

// ---- block-of-128 reductions (tree in LDS) --------------------------------
__device__ __forceinline__ float blk_sum128(float v, float* red) {
  int d = threadIdx.x;
  red[d] = v; __syncthreads();
  if (d < 64) red[d] += red[d + 64]; __syncthreads();
  if (d < 32) red[d] += red[d + 32]; __syncthreads();
  if (d < 16) red[d] += red[d + 16]; __syncthreads();
  if (d < 8)  red[d] += red[d + 8];  __syncthreads();
  if (d < 4)  red[d] += red[d + 4];  __syncthreads();
  if (d < 2)  red[d] += red[d + 2];  __syncthreads();
  if (d < 1)  red[d] += red[d + 1];  __syncthreads();
  float r = red[0]; __syncthreads();
  return r;
}
__device__ __forceinline__ float blk_max128(float v, float* red) {
  int d = threadIdx.x;
  red[d] = v; __syncthreads();
  if (d < 64) red[d] = fmaxf(red[d], red[d + 64]); __syncthreads();
  if (d < 32) red[d] = fmaxf(red[d], red[d + 32]); __syncthreads();
  if (d < 16) red[d] = fmaxf(red[d], red[d + 16]); __syncthreads();
  if (d < 8)  red[d] = fmaxf(red[d], red[d + 8]);  __syncthreads();
  if (d < 4)  red[d] = fmaxf(red[d], red[d + 4]);  __syncthreads();
  if (d < 2)  red[d] = fmaxf(red[d], red[d + 2]);  __syncthreads();
  if (d < 1)  red[d] = fmaxf(red[d], red[d + 1]);  __syncthreads();
  float r = red[0]; __syncthreads();
  return r;
}

// ---------------------------------------------------------------------------
// Reorder (L,3072)->(H,L,128) with optional per-head RMS norm (IP K/V).
// ---------------------------------------------------------------------------
__global__ __launch_bounds__(128) void ip_norm_reorder(
    const float* __restrict__ src, const float* __restrict__ w,
    float* __restrict__ dst, int do_norm) {
  __shared__ float red[128];
  const int t = blockIdx.x, h = blockIdx.y, d = threadIdx.x;
  float v = src[(size_t)t * HID + h * DH + d];
  if (do_norm) {
    float ss = blk_sum128(v * v, red);
    v = v * rsqrtf(ss * (1.0f / DH) + 1e-6f) * w[d];
  }
  dst[((size_t)h * IPL + t) * DH + d] = v;
}

// ---------------------------------------------------------------------------
// IP attention, bbox rows only (256 tokens). grid (256, 24), block 128.
// ---------------------------------------------------------------------------
__global__ __launch_bounds__(128) void ip_attn(
    const float* __restrict__ Q, const float* __restrict__ KN,
    const float* __restrict__ VN, const float* __restrict__ qw,
    float* __restrict__ OUTc) {
  const int b = blockIdx.x, h = blockIdx.y, d = threadIdx.x;
  const int y = 8 + (b >> 4), x = 8 + (b & 15);
  const int t = y * 32 + x;
  __shared__ float qs[128], ps[128], red[128];
  float qv = Q[(size_t)t * HID + h * DH + d];
  float ss = blk_sum128(qv * qv, red);
  qs[d] = qv * rsqrtf(ss * (1.0f / DH) + 1e-6f) * qw[d];
  __syncthreads();
  const float* krow = KN + ((size_t)h * IPL + d) * DH;
  float s = 0.f;
#pragma unroll 4
  for (int i = 0; i < 128; ++i) s += qs[i] * krow[i];
  s *= ATTN_SCALE;
  float mx = blk_max128(s, red);
  float p = __expf(s - mx);
  ps[d] = p;
  float lsum = blk_sum128(p, red);
  const float* vcol = VN + (size_t)h * IPL * DH + d;
  float o = 0.f;
#pragma unroll 4
  for (int j = 0; j < 128; ++j) o += ps[j] * vcol[(size_t)j * DH];
  OUTc[(size_t)b * HID + h * DH + d] = o / lsum;
}

// ---------------------------------------------------------------------------
// Fused per-head RMS + RoPE + split-bf16 convert, IN PLACE.
// ---------------------------------------------------------------------------
__global__ __launch_bounds__(768) void rmsrope_cvt(
    float* __restrict__ img, float* __restrict__ enc,
    const float* __restrict__ w_img, const float* __restrict__ w_enc,
    const float* __restrict__ cosb, const float* __restrict__ sinb, float scale) {
  const int s = blockIdx.x;
  const int t = threadIdx.x;
  float* row = (s < TXT) ? (enc + (size_t)s * HID) : (img + (size_t)(s - TXT) * HID);
  const float* w = (s < TXT) ? w_enc : w_img;
  const int dh = (t & 31) * 4;  // d within head
  float4 v = *(const float4*)(row + t * 4);
  float ss = v.x * v.x + v.y * v.y + v.z * v.z + v.w * v.w;
  ss += __shfl_xor(ss, 16); ss += __shfl_xor(ss, 8);
  ss += __shfl_xor(ss, 4);  ss += __shfl_xor(ss, 2); ss += __shfl_xor(ss, 1);
  float r = rsqrtf(ss * (1.0f / DH) + 1e-6f);
  float4 wv = *(const float4*)(w + dh);
  float n0 = v.x * r * wv.x, n1 = v.y * r * wv.y;
  float n2 = v.z * r * wv.z, n3 = v.w * r * wv.w;
  float4 cv = *(const float4*)(cosb + (size_t)s * DH + dh);
  float4 sv = *(const float4*)(sinb + (size_t)s * DH + dh);
  float o0 = (n0 * cv.x - n1 * sv.x) * scale;
  float o1 = (n1 * cv.y + n0 * sv.y) * scale;
  float o2 = (n2 * cv.z - n3 * sv.z) * scale;
  float o3 = (n3 * cv.w + n2 * sv.w) * scale;
  __syncthreads();  // all row reads complete before in-place overwrite
  unsigned h0 = pkbf(o0, o1), h1 = pkbf(o2, o3);
  float l0 = o0 - __uint_as_float(h0 << 16);
  float l1 = o1 - __uint_as_float(h0 & 0xffff0000u);
  float l2 = o2 - __uint_as_float(h1 << 16);
  float l3 = o3 - __uint_as_float(h1 & 0xffff0000u);
  unsigned lw0 = pkbf(l0, l1), lw1 = pkbf(l2, l3);
  unsigned* ur = (unsigned*)row;
  *(uint2*)(ur + t * 2) = make_uint2(h0, h1);
  *(uint2*)(ur + 1536 + t * 2) = make_uint2(lw0, lw1);
}

// ---------------------------------------------------------------------------
// V: fp32 -> per-head transposed bf16 hi/lo: VT[h][d][k], k enc-first order.
// ---------------------------------------------------------------------------
__global__ __launch_bounds__(256) void v_cvt_transpose(
    const float* __restrict__ Vimg, const float* __restrict__ Venc,
    u16* __restrict__ VTh, u16* __restrict__ VTl) {
  __shared__ float T[64][132];
  const int kc = blockIdx.x, h = blockIdx.y, tid = threadIdx.x;
  {
    const int r = tid >> 2, c = tid & 3;
    const int kk = kc * 64 + r;
    const float* src = ((kk < TXT) ? (Venc + (size_t)kk * HID)
                                   : (Vimg + (size_t)(kk - TXT) * HID)) + h * DH + c * 32;
#pragma unroll
    for (int i = 0; i < 8; ++i)
      *(float4*)&T[r][c * 32 + i * 4] = *(const float4*)(src + i * 4);
  }
  __syncthreads();
  const int d = tid >> 1, kh = tid & 1;
  unsigned hw[16], lw[16];
#pragma unroll
  for (int i = 0; i < 16; ++i) {
    float a = T[kh * 32 + i * 2 + 0][d];
    float b = T[kh * 32 + i * 2 + 1][d];
    unsigned hh = pkbf(a, b);
    float la = a - __uint_as_float(hh << 16);
    float lb = b - __uint_as_float(hh & 0xffff0000u);
    hw[i] = hh; lw[i] = pkbf(la, lb);
  }
  size_t base = ((size_t)h * DH + d) * SFULL + kc * 64 + kh * 32;
#pragma unroll
  for (int i = 0; i < 4; ++i) {
    *(uint4*)(VTh + base + i * 8) = make_uint4(hw[i*4], hw[i*4+1], hw[i*4+2], hw[i*4+3]);
    *(uint4*)(VTl + base + i * 8) = make_uint4(lw[i*4], lw[i*4+1], lw[i*4+2], lw[i*4+3]);
  }
}

// ---------------------------------------------------------------------------
// MFMA flash attention. grid flat 576 blocks (XCD-swizzled: 3 heads/XCD),
// 256 thr = 4 waves. QBLK=64 (16 q/wave), KVB=32. Split-bf16 everywhere.
// __launch_bounds__(256,3): LDS caps at 3 blocks/CU = 3 waves/EU anyway;
// this raises the VGPR cap to ~168 so the stage-ahead regs never spill.
// ---------------------------------------------------------------------------
#define KVB 32
#define NKT (SFULL / KVB)  // 48

__global__ __launch_bounds__(256, 3) void flash_mfma(
    const float* __restrict__ Qimg, const float* __restrict__ Qenc,
    const float* __restrict__ Kimg, const float* __restrict__ Kenc,
    const u16* __restrict__ VTh, const u16* __restrict__ VTl,
    const float* __restrict__ IPOc, float* __restrict__ AOUT) {
  __shared__ __align__(16) u16 Klds[2][KVB * 128];   // [plane], XOR-swizzled rows
  __shared__ __align__(16) u16 Vlds[2][128 * 40];    // [plane][d*40+k], pad 80B
  __shared__ __align__(16) u16 Plds[4][2][16 * 40];  // [wave][plane][q*40+k]
  const int tid = threadIdx.x;
  const int lane = tid & 63, w = tid >> 6;
  // XCD swizzle: consecutive sw ids on one XCD; head = sw/24 -> 3 heads/XCD
  const int sw = xcd_swz(blockIdx.y * gridDim.x + blockIdx.x, 24 * NH);
  const int h = sw / 24;
  const int q0 = (sw % 24) * 64;
  const int l15 = lane & 15, lg = lane >> 4;

  // ---- Q fragments in registers (4 k-steps x hi/lo), scaled already
  bf16x8 qf[4][2];
  {
    const int qrow = q0 + w * 16 + l15;
    const u16* rp = (qrow < TXT) ? (const u16*)(Qenc + (size_t)qrow * HID)
                                 : (const u16*)(Qimg + (size_t)(qrow - TXT) * HID);
#pragma unroll
    for (int ks = 0; ks < 4; ++ks) {
      qf[ks][0] = *(const bf16x8*)(rp + h * DH + ks * 32 + lg * 8);
      qf[ks][1] = *(const bf16x8*)(rp + 3072 + h * DH + ks * 32 + lg * 8);
    }
  }

  f32x4 O[8];
#pragma unroll
  for (int i = 0; i < 8; ++i) O[i] = (f32x4){0.f, 0.f, 0.f, 0.f};
  float mrun[4], lrun[4];
#pragma unroll
  for (int j = 0; j < 4; ++j) { mrun[j] = -1e30f; lrun[j] = 0.f; }

  uint4 kr[4], vr[4];
  // stage_load: fetch tile kt into regs (K: 32x128x2 planes; V: 128x32x2)
#define STAGE_LOAD(kt)                                                          \
  {                                                                             \
    _Pragma("unroll")                                                           \
    for (int it = 0; it < 4; ++it) {                                            \
      const int c = tid + it * 256;                                             \
      const int pl = c >> 9, rowk = (c >> 4) & 31, ch = c & 15;                 \
      const int kk = (kt) * KVB + rowk;                                         \
      const u16* rp = (kk < TXT) ? (const u16*)(Kenc + (size_t)kk * HID)        \
                                 : (const u16*)(Kimg + (size_t)(kk - TXT) * HID); \
      kr[it] = *(const uint4*)(rp + pl * 3072 + h * DH + ch * 8);               \
      const int dv = (c >> 2) & 127, cv = c & 3;                                \
      const u16* vp = (pl ? VTl : VTh) + ((size_t)h * DH + dv) * SFULL          \
                      + (kt) * KVB + cv * 8;                                    \
      vr[it] = *(const uint4*)vp;                                               \
    }                                                                           \
  }

  STAGE_LOAD(0)
  for (int kt = 0; kt < NKT; ++kt) {
    __syncthreads();  // all waves done reading previous tile's LDS
    // ---- write staged regs to LDS
#pragma unroll
    for (int it = 0; it < 4; ++it) {
      const int c = tid + it * 256;
      const int pl = c >> 9, rowk = (c >> 4) & 31, ch = c & 15;
      *(uint4*)((char*)&Klds[pl][0] + ((rowk * 256 + ch * 16) ^ ((rowk & 7) << 4))) = kr[it];
      const int dv = (c >> 2) & 127, cv = c & 3;
      *(uint4*)&Vlds[pl][dv * 40 + cv * 8] = vr[it];
    }
    // straight-line prefetch (clamped at last tile; re-load hits L2, cheap).
    // Unconditional -> clean register lifetimes, no spill.
    const int ktn = (kt + 1 < NKT) ? kt + 1 : kt;
    STAGE_LOAD(ktn)
    __syncthreads();

    // ---- QK^T: S strip 16q x 32k per wave
    f32x4 sA[2] = {(f32x4){0.f, 0.f, 0.f, 0.f}, (f32x4){0.f, 0.f, 0.f, 0.f}};
#pragma unroll
    for (int ks = 0; ks < 4; ++ks)
#pragma unroll
      for (int fn = 0; fn < 2; ++fn) {
        const int krow = fn * 16 + l15;
        const int off = (krow * 256 + ks * 64 + lg * 16) ^ ((krow & 7) << 4);
        bf16x8 kh = *(const bf16x8*)((const char*)&Klds[0][0] + off);
        bf16x8 kl = *(const bf16x8*)((const char*)&Klds[1][0] + off);
        sA[fn] = __builtin_amdgcn_mfma_f32_16x16x32_bf16(qf[ks][0], kh, sA[fn], 0, 0, 0);
        sA[fn] = __builtin_amdgcn_mfma_f32_16x16x32_bf16(qf[ks][1], kh, sA[fn], 0, 0, 0);
        sA[fn] = __builtin_amdgcn_mfma_f32_16x16x32_bf16(qf[ks][0], kl, sA[fn], 0, 0, 0);
      }

    // ---- online softmax, wave-parallel (rows q=lg*4+j, cols k across lanes)
#pragma unroll
    for (int j = 0; j < 4; ++j) {
      float v0 = sA[0][j], v1 = sA[1][j];
      float mx = fmaxf(v0, v1);
      mx = fmaxf(mx, __shfl_xor(mx, 1));
      mx = fmaxf(mx, __shfl_xor(mx, 2));
      mx = fmaxf(mx, __shfl_xor(mx, 4));
      mx = fmaxf(mx, __shfl_xor(mx, 8));
      float mnew = fmaxf(mrun[j], mx);
      float a = __expf(mrun[j] - mnew);
      mrun[j] = mnew;
      float p0 = __expf(v0 - mnew), p1 = __expf(v1 - mnew);
      float ts = p0 + p1;
      ts += __shfl_xor(ts, 1); ts += __shfl_xor(ts, 2);
      ts += __shfl_xor(ts, 4); ts += __shfl_xor(ts, 8);
      lrun[j] = lrun[j] * a + ts;
#pragma unroll
      for (int fn = 0; fn < 8; ++fn) O[fn][j] *= a;
      // P -> hi/lo bf16 into per-wave LDS strip [q][k]
      unsigned hp0 = pkbf(p0, 0.f), hp1 = pkbf(p1, 0.f);
      float lp0 = p0 - __uint_as_float(hp0 << 16);
      float lp1 = p1 - __uint_as_float(hp1 << 16);
      unsigned lo0 = pkbf(lp0, 0.f), lo1 = pkbf(lp1, 0.f);
      const int q = lg * 4 + j;
      Plds[w][0][q * 40 + l15]      = (u16)hp0;
      Plds[w][0][q * 40 + 16 + l15] = (u16)hp1;
      Plds[w][1][q * 40 + l15]      = (u16)lo0;
      Plds[w][1][q * 40 + 16 + l15] = (u16)lo1;
    }

    // ---- P @ V  (A = P strip, B = VT tile)
    bf16x8 pa0 = *(const bf16x8*)&Plds[w][0][l15 * 40 + lg * 8];
    bf16x8 pa1 = *(const bf16x8*)&Plds[w][1][l15 * 40 + lg * 8];
#pragma unroll
    for (int fn = 0; fn < 8; ++fn) {
      const int dd = fn * 16 + l15;
      bf16x8 vh = *(const bf16x8*)&Vlds[0][dd * 40 + lg * 8];
      bf16x8 vl = *(const bf16x8*)&Vlds[1][dd * 40 + lg * 8];
      O[fn] = __builtin_amdgcn_mfma_f32_16x16x32_bf16(pa0, vh, O[fn], 0, 0, 0);
      O[fn] = __builtin_amdgcn_mfma_f32_16x16x32_bf16(pa1, vh, O[fn], 0, 0, 0);
      O[fn] = __builtin_amdgcn_mfma_f32_16x16x32_bf16(pa0, vl, O[fn], 0, 0, 0);
    }
  }
#undef STAGE_LOAD

  // ---- epilogue: normalize, add compact IP output on bbox rows, store fp32
#pragma unroll
  for (int j = 0; j < 4; ++j) {
    const float inv = 1.0f / lrun[j];
    const int s = q0 + w * 16 + lg * 4 + j;
    float* orow = AOUT + (size_t)s * HID + h * DH;
    const float* iprow = nullptr;
    if (s >= TXT) {
      const int t2 = s - TXT, y = t2 >> 5, x = t2 & 31;
      if (y >= 8 && y < 24 && x >= 8 && x < 24)
        iprow = IPOc + (size_t)((y - 8) * 16 + (x - 8)) * HID + h * DH;
    }
#pragma unroll
    for (int fn = 0; fn < 8; ++fn) {
      float val = O[fn][j] * inv;
      const int dd = fn * 16 + l15;
      if (iprow) val += iprow[dd];
      orow[dd] = val;
    }
  }
}

// ---------------------------------------------------------------------------
extern "C" void kernel_launch(void* const* d_in, const int* in_sizes, int n_in,
                              void* d_out, int out_size, void* d_ws, size_t ws_size,
                              hipStream_t stream) {
  const float* x    = (const float*)d_in[0];
  const float* enc  = (const float*)d_in[1];
  const float* ip   = (const float*)d_in[2];
  const float* cosb = (const float*)d_in[3];
  const float* sinb = (const float*)d_in[4];
  const float* Wq   = (const float*)d_in[5];
  const float* bq   = (const float*)d_in[6];
  const float* Wk   = (const float*)d_in[7];
  const float* bk   = (const float*)d_in[8];
  const float* Wv   = (const float*)d_in[9];
  const float* bv   = (const float*)d_in[10];
  const float* nqw  = (const float*)d_in[11];
  const float* nkw  = (const float*)d_in[12];
  const float* Wqa  = (const float*)d_in[13];
  const float* bqa  = (const float*)d_in[14];
  const float* Wka  = (const float*)d_in[15];
  const float* bka  = (const float*)d_in[16];
  const float* Wva  = (const float*)d_in[17];
  const float* bva  = (const float*)d_in[18];
  const float* naqw = (const float*)d_in[19];
  const float* nakw = (const float*)d_in[20];
  const float* Wo   = (const float*)d_in[21];
  const float* bo   = (const float*)d_in[22];
  const float* Wao  = (const float*)d_in[23];
  const float* bao  = (const float*)d_in[24];
  const float* Wkip = (const float*)d_in[25];
  const float* bkip = (const float*)d_in[26];
  const float* Wvip = (const float*)d_in[27];
  const float* bvip = (const float*)d_in[28];
  const float* nipq = (const float*)d_in[29];
  const float* nipk = (const float*)d_in[30];

  float* out_img = (float*)d_out;                       // (1024, 3072)
  float* out_enc = (float*)d_out + (size_t)SIMG * HID;  // (512, 3072)

  float* ws = (float*)d_ws;
  // workspace layout (float offsets), total 19,660,800 floats = 78.6 MB
  float* Qi  = ws + 0;          // img Q fp32 -> packed hi|lo bf16 (1024 rows)
  float* Qe  = ws + 3145728;    // enc Q (512 rows)
  float* Ki  = ws + 4718592;    // img K
  float* Ke  = ws + 7864320;    // enc K
  float* Vi  = ws + 9437184;    // img V  }-> AOUT (1536 rows) after transpose
  float* Ve  = ws + 12582912;   // enc V  }
  float* VTr = ws + 14155776;   // VT region: 4,718,592 floats
  float* IPOc= ws + 18874368;   // compact IP out (256 x 3072)
  // temporaries inside the VT region (dead before v_cvt_transpose runs):
  float* KIP  = VTr;                 // 128x3072
  float* VIP  = VTr + 393216;        // 128x3072
  float* KIPN = VTr + 786432;        // (24,128,128)
  float* VIPN = VTr + 1179648;       // (24,128,128)
  u16* VTh = (u16*)VTr;              // (24,128,1536) hi
  u16* VTl = (u16*)(VTr + 2359296);  // (24,128,1536) lo
  float* AOUT = Vi;                  // rows: 0..511 enc, 512..1535 img

  dim3 blk256(256), blk128(128);

  // 1. QKV projections (img + enc), fused col-segmented MFMA launches
  gemm_seg3<<<dim3(72, 8), blk256, 0, stream>>>(
      x, Seg3{Wq, Wk, Wv, bq, bk, bv, Qi, Ki, Vi}, HID);
  gemm_seg3<<<dim3(72, 4), blk256, 0, stream>>>(
      enc, Seg3{Wqa, Wka, Wva, bqa, bka, bva, Qe, Ke, Ve}, HID);
  // 2. IP K/V projections + normalize/reorder + IP attention (raw fp32 Q)
  gemm_seg3<<<dim3(48, 1), blk256, 0, stream>>>(
      ip, Seg3{Wkip, Wvip, Wvip, bkip, bvip, bvip, KIP, VIP, VIP}, IPD);
  ip_norm_reorder<<<dim3(IPL, NH), blk128, 0, stream>>>(KIP, nipk, KIPN, 1);
  ip_norm_reorder<<<dim3(IPL, NH), blk128, 0, stream>>>(VIP, nullptr, VIPN, 0);
  ip_attn<<<dim3(256, NH), blk128, 0, stream>>>(Qi, KIPN, VIPN, nipq, IPOc);
  // 3. RMS+RoPE+split-bf16 convert in place (Q pre-scaled); V -> VT hi/lo
  rmsrope_cvt<<<dim3(SFULL), dim3(768), 0, stream>>>(Qi, Qe, nqw, naqw, cosb, sinb, ATTN_SCALE);
  rmsrope_cvt<<<dim3(SFULL), dim3(768), 0, stream>>>(Ki, Ke, nkw, nakw, cosb, sinb, 1.0f);
  v_cvt_transpose<<<dim3(24, NH), blk256, 0, stream>>>(Vi, Ve, VTh, VTl);
  // 4. MFMA flash attention (adds compact IP output on bbox rows)
  flash_mfma<<<dim3(24, NH), blk256, 0, stream>>>(Qi, Qe, Ki, Ke, VTh, VTl, IPOc, AOUT);
  // 5. fused output projections (row-segmented: enc rows -> Wao, img -> Wo)
  gemm_out2<<<dim3(24, 12), blk256, 0, stream>>>(
      AOUT, Wao, bao, out_enc, Wo, bo, out_img, HID);
}

// Round 4
// 1402.323 us; speedup vs baseline: 2.6340x; 1.0651x over previous
//
#include <hip/hip_runtime.h>

// ---------------------------------------------------------------------------
// FluxIPAttnProcessor — round 7: flash_mfma staging via global_load_lds DMA.
// Round-6 post-mortem: WRITE_SIZE still 706 MB = kr[]/vr[] reg-staging spilled
// to scratch (VGPR=80; launch_bounds hint ignored). Fix: no staging registers
// at all — __builtin_amdgcn_global_load_lds with linear LDS dest + inverse-
// swizzled per-lane global SOURCE (rule #21), double-buffered 2x36KB + 8KB P
// = 80 KB exactly (2 blocks/CU). One raw s_barrier per tile, counted vmcnt
// after compute (m201 pattern), sched_barrier(0) fences.
// ---------------------------------------------------------------------------

#define HID 3072
#define DH 128
#define NH 24
#define TXT 512
#define SIMG 1024
#define SFULL 1536
#define IPL 128
#define IPD 1152
#define ATTN_SCALE 0.08838834764831845f  // 1/sqrt(128)

typedef unsigned short u16;
typedef __attribute__((ext_vector_type(8))) short bf16x8;
typedef __attribute__((ext_vector_type(4))) float f32x4;

// GEMM LDS row stride in shorts: 32 data + 8 pad = 80 B (odd multiple of 16B)
#define LDST 40

// XCD-bijective block swizzle (requires nwg % 8 == 0; all our grids comply).
__device__ __forceinline__ int xcd_swz(int flat, int nwg) {
  return (flat & 7) * (nwg >> 3) + (flat >> 3);
}

// HBM -> LDS 16B DMA: per-lane global src, wave-uniform LDS base (+lane*16).
__device__ __forceinline__ void gload16(const void* src, void* dst) {
  __builtin_amdgcn_global_load_lds(
      (const __attribute__((address_space(1))) void*)(void*)src,
      (__attribute__((address_space(3))) void*)dst, 16, 0, 0);
}

// packed fp32->bf16 RNE: low 16 = bf16(a), high 16 = bf16(b)
__device__ __forceinline__ unsigned pkbf(float a, float b) {
  unsigned r;
  asm("v_cvt_pk_bf16_f32 %0, %1, %2" : "=v"(r) : "v"(a), "v"(b));
  return r;
}

// 8 floats -> 8 hi-bf16 (16B) + 8 lo-bf16 (16B). lo = x - float(hi), exact.
__device__ __forceinline__ void cvt_hi_lo(float4 fa, float4 fb, uint4* hi, uint4* lo) {
  unsigned h0 = pkbf(fa.x, fa.y), h1 = pkbf(fa.z, fa.w);
  unsigned h2 = pkbf(fb.x, fb.y), h3 = pkbf(fb.z, fb.w);
  float r0 = fa.x - __uint_as_float(h0 << 16);
  float r1 = fa.y - __uint_as_float(h0 & 0xffff0000u);
  float r2 = fa.z - __uint_as_float(h1 << 16);
  float r3 = fa.w - __uint_as_float(h1 & 0xffff0000u);
  float r4 = fb.x - __uint_as_float(h2 << 16);
  float r5 = fb.y - __uint_as_float(h2 & 0xffff0000u);
  float r6 = fb.z - __uint_as_float(h3 << 16);
  float r7 = fb.w - __uint_as_float(h3 & 0xffff0000u);
  *hi = make_uint4(h0, h1, h2, h3);
  *lo = make_uint4(pkbf(r0, r1), pkbf(r2, r3), pkbf(r4, r5), pkbf(r6, r7));
}

// ---------------------------------------------------------------------------
// 128x128 tile GEMM core (harness-verified rounds 4-6).
// ---------------------------------------------------------------------------
__device__ __forceinline__ void gemm128_core(
    const float* __restrict__ A, const float* __restrict__ W,
    const float* __restrict__ bias, float* __restrict__ C, int K, int ldC) {
  __shared__ short Ah[128 * LDST], Al[128 * LDST];
  __shared__ short Wh[128 * LDST], Wl[128 * LDST];
  const int tid = threadIdx.x;
  const int srow = tid >> 1;
  const int skb = (tid & 1) * 16;
  const int sidx = srow * LDST + skb;
  const int lane = tid & 63, w = tid >> 6;
  const int wm = (w >> 1) * 64, wn = (w & 1) * 64;
  const int fr = lane & 15, kg = lane >> 4;
  const int aoff = (wm + fr) * LDST + kg * 8;
  const int boff = (wn + fr) * LDST + kg * 8;
  const float* ap = A + (size_t)srow * K + skb;
  const float* wp = W + (size_t)srow * K + skb;

  f32x4 acc[4][4];
#pragma unroll
  for (int i = 0; i < 4; ++i)
#pragma unroll
    for (int j = 0; j < 4; ++j) acc[i][j] = (f32x4){0.f, 0.f, 0.f, 0.f};

  for (int k0 = 0; k0 < K; k0 += 32) {
    float4 a0 = *(const float4*)(ap + k0);
    float4 a1 = *(const float4*)(ap + k0 + 4);
    float4 a2 = *(const float4*)(ap + k0 + 8);
    float4 a3 = *(const float4*)(ap + k0 + 12);
    float4 b0 = *(const float4*)(wp + k0);
    float4 b1 = *(const float4*)(wp + k0 + 4);
    float4 b2 = *(const float4*)(wp + k0 + 8);
    float4 b3 = *(const float4*)(wp + k0 + 12);
    uint4 h, l;
    cvt_hi_lo(a0, a1, &h, &l);
    *(uint4*)&Ah[sidx] = h;     *(uint4*)&Al[sidx] = l;
    cvt_hi_lo(a2, a3, &h, &l);
    *(uint4*)&Ah[sidx + 8] = h; *(uint4*)&Al[sidx + 8] = l;
    cvt_hi_lo(b0, b1, &h, &l);
    *(uint4*)&Wh[sidx] = h;     *(uint4*)&Wl[sidx] = l;
    cvt_hi_lo(b2, b3, &h, &l);
    *(uint4*)&Wh[sidx + 8] = h; *(uint4*)&Wl[sidx + 8] = l;
    __syncthreads();
    bf16x8 fah[4], fal[4], fbh[4], fbl[4];
#pragma unroll
    for (int f = 0; f < 4; ++f) {
      fah[f] = *(const bf16x8*)&Ah[aoff + f * 16 * LDST];
      fal[f] = *(const bf16x8*)&Al[aoff + f * 16 * LDST];
      fbh[f] = *(const bf16x8*)&Wh[boff + f * 16 * LDST];
      fbl[f] = *(const bf16x8*)&Wl[boff + f * 16 * LDST];
    }
#pragma unroll
    for (int fm = 0; fm < 4; ++fm)
#pragma unroll
      for (int fn = 0; fn < 4; ++fn) {
        acc[fm][fn] = __builtin_amdgcn_mfma_f32_16x16x32_bf16(fah[fm], fbh[fn], acc[fm][fn], 0, 0, 0);
        acc[fm][fn] = __builtin_amdgcn_mfma_f32_16x16x32_bf16(fal[fm], fbh[fn], acc[fm][fn], 0, 0, 0);
        acc[fm][fn] = __builtin_amdgcn_mfma_f32_16x16x32_bf16(fah[fm], fbl[fn], acc[fm][fn], 0, 0, 0);
      }
    __syncthreads();
  }
  const int r4 = kg * 4;
#pragma unroll
  for (int fn = 0; fn < 4; ++fn) {
    float bb = bias[wn + fn * 16 + fr];
#pragma unroll
    for (int fm = 0; fm < 4; ++fm) {
      f32x4 v = acc[fm][fn];
#pragma unroll
      for (int j = 0; j < 4; ++j)
        C[(size_t)(wm + fm * 16 + r4 + j) * ldC + (wn + fn * 16 + fr)] = v[j] + bb;
    }
  }
}

struct Seg3 {
  const float *W0, *W1, *W2;
  const float *b0, *b1, *b2;
  float *C0, *C1, *C2;
};

__global__ __launch_bounds__(256) void gemm_seg3(const float* __restrict__ A, Seg3 s, int K) {
  const int nwg = gridDim.x * gridDim.y;
  const int sw = xcd_swz(blockIdx.y * gridDim.x + blockIdx.x, nwg);
  const int by = sw % gridDim.y;        // m tile (fastest)
  const int bx = sw / gridDim.y;        // seg*24 + n tile
  const int seg = bx / 24;
  const int n0 = (bx % 24) * 128;
  const int m0 = by * 128;
  const float* W = seg == 0 ? s.W0 : (seg == 1 ? s.W1 : s.W2);
  const float* b = seg == 0 ? s.b0 : (seg == 1 ? s.b1 : s.b2);
  float* C = seg == 0 ? s.C0 : (seg == 1 ? s.C1 : s.C2);
  gemm128_core(A + (size_t)m0 * K, W + (size_t)n0 * K, b + n0,
               C + (size_t)m0 * HID + n0, K, HID);
}

__global__ __launch_bounds__(256) void gemm_out2(
    const float* __restrict__ A,
    const float* __restrict__ We, const float* __restrict__ be, float* __restrict__ Ce,
    const float* __restrict__ Wi, const float* __restrict__ bi, float* __restrict__ Ci,
    int K) {
  const int nwg = gridDim.x * gridDim.y;
  const int sw = xcd_swz(blockIdx.y * gridDim.x + blockIdx.x, nwg);
  const int by = sw % gridDim.y;        // m tile (fastest)
  const int bx = sw / gridDim.y;        // n tile
  const int m0 = by * 128;
  const int n0 = bx * 128;
  const float* W; const float* b; float* C; int cr;
  if (m0 < TXT) { W = We; b = be; C = Ce; cr = m0; }
  else          { W = Wi; b = bi; C = Ci; cr = m0 - TXT; }
  gemm128_core(A + (size_t)m0 * K, W + (size_t)n0 * K, b + n0,
               C + (size_t)cr * HID + n0, K, HID);
}

// ---- block-of-128 reductions (tree in LDS) --------------------------------
__device__ __forceinline__ float blk_sum128(float v, float* red) {
  int d = threadIdx.x;
  red[d] = v; __syncthreads();
  if (d < 64) red[d] += red[d + 64]; __syncthreads();
  if (d < 32) red[d] += red[d + 32]; __syncthreads();
  if (d < 16) red[d] += red[d + 16]; __syncthreads();
  if (d < 8)  red[d] += red[d + 8];  __syncthreads();
  if (d < 4)  red[d] += red[d + 4];  __syncthreads();
  if (d < 2)  red[d] += red[d + 2];  __syncthreads();
  if (d < 1)  red[d] += red[d + 1];  __syncthreads();
  float r = red[0]; __syncthreads();
  return r;
}
__device__ __forceinline__ float blk_max128(float v, float* red) {
  int d = threadIdx.x;
  red[d] = v; __syncthreads();
  if (d < 64) red[d] = fmaxf(red[d], red[d + 64]); __syncthreads();
  if (d < 32) red[d] = fmaxf(red[d], red[d + 32]); __syncthreads();
  if (d < 16) red[d] = fmaxf(red[d], red[d + 16]); __syncthreads();
  if (d < 8)  red[d] = fmaxf(red[d], red[d + 8]);  __syncthreads();
  if (d < 4)  red[d] = fmaxf(red[d], red[d + 4]);  __syncthreads();
  if (d < 2)  red[d] = fmaxf(red[d], red[d + 2]);  __syncthreads();
  if (d < 1)  red[d] = fmaxf(red[d], red[d + 1]);  __syncthreads();
  float r = red[0]; __syncthreads();
  return r;
}

// ---------------------------------------------------------------------------
// Reorder (L,3072)->(H,L,128) with optional per-head RMS norm (IP K/V).
// ---------------------------------------------------------------------------
__global__ __launch_bounds__(128) void ip_norm_reorder(
    const float* __restrict__ src, const float* __restrict__ w,
    float* __restrict__ dst, int do_norm) {
  __shared__ float red[128];
  const int t = blockIdx.x, h = blockIdx.y, d = threadIdx.x;
  float v = src[(size_t)t * HID + h * DH + d];
  if (do_norm) {
    float ss = blk_sum128(v * v, red);
    v = v * rsqrtf(ss * (1.0f / DH) + 1e-6f) * w[d];
  }
  dst[((size_t)h * IPL + t) * DH + d] = v;
}

// ---------------------------------------------------------------------------
// IP attention, bbox rows only (256 tokens). grid (256, 24), block 128.
// ---------------------------------------------------------------------------
__global__ __launch_bounds__(128) void ip_attn(
    const float* __restrict__ Q, const float* __restrict__ KN,
    const float* __restrict__ VN, const float* __restrict__ qw,
    float* __restrict__ OUTc) {
  const int b = blockIdx.x, h = blockIdx.y, d = threadIdx.x;
  const int y = 8 + (b >> 4), x = 8 + (b & 15);
  const int t = y * 32 + x;
  __shared__ float qs[128], ps[128], red[128];
  float qv = Q[(size_t)t * HID + h * DH + d];
  float ss = blk_sum128(qv * qv, red);
  qs[d] = qv * rsqrtf(ss * (1.0f / DH) + 1e-6f) * qw[d];
  __syncthreads();
  const float* krow = KN + ((size_t)h * IPL + d) * DH;
  float s = 0.f;
#pragma unroll 4
  for (int i = 0; i < 128; ++i) s += qs[i] * krow[i];
  s *= ATTN_SCALE;
  float mx = blk_max128(s, red);
  float p = __expf(s - mx);
  ps[d] = p;
  float lsum = blk_sum128(p, red);
  const float* vcol = VN + (size_t)h * IPL * DH + d;
  float o = 0.f;
#pragma unroll 4
  for (int j = 0; j < 128; ++j) o += ps[j] * vcol[(size_t)j * DH];
  OUTc[(size_t)b * HID + h * DH + d] = o / lsum;
}

// ---------------------------------------------------------------------------
// Fused per-head RMS + RoPE + split-bf16 convert, IN PLACE.
// ---------------------------------------------------------------------------
__global__ __launch_bounds__(768) void rmsrope_cvt(
    float* __restrict__ img, float* __restrict__ enc,
    const float* __restrict__ w_img, const float* __restrict__ w_enc,
    const float* __restrict__ cosb, const float* __restrict__ sinb, float scale) {
  const int s = blockIdx.x;
  const int t = threadIdx.x;
  float* row = (s < TXT) ? (enc + (size_t)s * HID) : (img + (size_t)(s - TXT) * HID);
  const float* w = (s < TXT) ? w_enc : w_img;
  const int dh = (t & 31) * 4;  // d within head
  float4 v = *(const float4*)(row + t * 4);
  float ss = v.x * v.x + v.y * v.y + v.z * v.z + v.w * v.w;
  ss += __shfl_xor(ss, 16); ss += __shfl_xor(ss, 8);
  ss += __shfl_xor(ss, 4);  ss += __shfl_xor(ss, 2); ss += __shfl_xor(ss, 1);
  float r = rsqrtf(ss * (1.0f / DH) + 1e-6f);
  float4 wv = *(const float4*)(w + dh);
  float n0 = v.x * r * wv.x, n1 = v.y * r * wv.y;
  float n2 = v.z * r * wv.z, n3 = v.w * r * wv.w;
  float4 cv = *(const float4*)(cosb + (size_t)s * DH + dh);
  float4 sv = *(const float4*)(sinb + (size_t)s * DH + dh);
  float o0 = (n0 * cv.x - n1 * sv.x) * scale;
  float o1 = (n1 * cv.y + n0 * sv.y) * scale;
  float o2 = (n2 * cv.z - n3 * sv.z) * scale;
  float o3 = (n3 * cv.w + n2 * sv.w) * scale;
  __syncthreads();  // all row reads complete before in-place overwrite
  unsigned h0 = pkbf(o0, o1), h1 = pkbf(o2, o3);
  float l0 = o0 - __uint_as_float(h0 << 16);
  float l1 = o1 - __uint_as_float(h0 & 0xffff0000u);
  float l2 = o2 - __uint_as_float(h1 << 16);
  float l3 = o3 - __uint_as_float(h1 & 0xffff0000u);
  unsigned lw0 = pkbf(l0, l1), lw1 = pkbf(l2, l3);
  unsigned* ur = (unsigned*)row;
  *(uint2*)(ur + t * 2) = make_uint2(h0, h1);
  *(uint2*)(ur + 1536 + t * 2) = make_uint2(lw0, lw1);
}

// ---------------------------------------------------------------------------
// V: fp32 -> per-head transposed bf16 hi/lo: VT[h][d][k], k enc-first order.
// ---------------------------------------------------------------------------
__global__ __launch_bounds__(256) void v_cvt_transpose(
    const float* __restrict__ Vimg, const float* __restrict__ Venc,
    u16* __restrict__ VTh, u16* __restrict__ VTl) {
  __shared__ float T[64][132];
  const int kc = blockIdx.x, h = blockIdx.y, tid = threadIdx.x;
  {
    const int r = tid >> 2, c = tid & 3;
    const int kk = kc * 64 + r;
    const float* src = ((kk < TXT) ? (Venc + (size_t)kk * HID)
                                   : (Vimg + (size_t)(kk - TXT) * HID)) + h * DH + c * 32;
#pragma unroll
    for (int i = 0; i < 8; ++i)
      *(float4*)&T[r][c * 32 + i * 4] = *(const float4*)(src + i * 4);
  }
  __syncthreads();
  const int d = tid >> 1, kh = tid & 1;
  unsigned hw[16], lw[16];
#pragma unroll
  for (int i = 0; i < 16; ++i) {
    float a = T[kh * 32 + i * 2 + 0][d];
    float b = T[kh * 32 + i * 2 + 1][d];
    unsigned hh = pkbf(a, b);
    float la = a - __uint_as_float(hh << 16);
    float lb = b - __uint_as_float(hh & 0xffff0000u);
    hw[i] = hh; lw[i] = pkbf(la, lb);
  }
  size_t base = ((size_t)h * DH + d) * SFULL + kc * 64 + kh * 32;
#pragma unroll
  for (int i = 0; i < 4; ++i) {
    *(uint4*)(VTh + base + i * 8) = make_uint4(hw[i*4], hw[i*4+1], hw[i*4+2], hw[i*4+3]);
    *(uint4*)(VTl + base + i * 8) = make_uint4(lw[i*4], lw[i*4+1], lw[i*4+2], lw[i*4+3]);
  }
}

// ---------------------------------------------------------------------------
// MFMA flash attention. grid flat 576 (XCD-swizzled: 3 heads/XCD), 256 thr =
// 4 waves. QBLK=64 (16 q/wave), KVB=32. Split-bf16 everywhere.
// Staging: global_load_lds DMA, double-buffered. Per buffer (36 KB, 36 x 1KB
// chunks, 9 per wave): [Kh 8KB][Kl 8KB][Vh 10KB][Vl 10KB]. K swizzle done by
// inverse-permuting the per-lane GLOBAL source (linear LDS dest); V rows are
// 80 B (5 chunks; 5th is pad, loaded with dup data, never read).
// One s_barrier per tile; vmcnt(0) after compute (latency hidden).
// ---------------------------------------------------------------------------
#define KVB 32
#define NKT (SFULL / KVB)  // 48

__global__ __launch_bounds__(256) void flash_mfma(
    const float* __restrict__ Qimg, const float* __restrict__ Qenc,
    const float* __restrict__ Kimg, const float* __restrict__ Kenc,
    const u16* __restrict__ VTh, const u16* __restrict__ VTl,
    const float* __restrict__ IPOc, float* __restrict__ AOUT) {
  // per buffer: Kh u16[4096] | Kl u16[4096] | Vh u16[5120] | Vl u16[5120]
  __shared__ __align__(16) u16 Stage[2][18432];      // 2 x 36864 B
  __shared__ __align__(16) u16 Plds[4][2][16 * 32];  // 8192 B
  const int tid = threadIdx.x;
  const int lane = tid & 63, w = tid >> 6;
  const int sw = xcd_swz(blockIdx.y * gridDim.x + blockIdx.x, 24 * NH);
  const int h = sw / 24;
  const int q0 = (sw % 24) * 64;
  const int l15 = lane & 15, lg = lane >> 4;

  // ---- Q fragments in registers (4 k-steps x hi/lo), pre-scaled
  bf16x8 qf[4][2];
  {
    const int qrow = q0 + w * 16 + l15;
    const u16* rp = (qrow < TXT) ? (const u16*)(Qenc + (size_t)qrow * HID)
                                 : (const u16*)(Qimg + (size_t)(qrow - TXT) * HID);
#pragma unroll
    for (int ks = 0; ks < 4; ++ks) {
      qf[ks][0] = *(const bf16x8*)(rp + h * DH + ks * 32 + lg * 8);
      qf[ks][1] = *(const bf16x8*)(rp + 3072 + h * DH + ks * 32 + lg * 8);
    }
  }

  f32x4 O[8];
#pragma unroll
  for (int i = 0; i < 8; ++i) O[i] = (f32x4){0.f, 0.f, 0.f, 0.f};
  float mrun[4], lrun[4];
#pragma unroll
  for (int j = 0; j < 4; ++j) { mrun[j] = -1e30f; lrun[j] = 0.f; }

  // ---- stage tile kt into LDS buffer via DMA (9 x 1KB chunks per wave)
  auto stage_issue = [&](int kt, u16* dstbase) {
    const int kr0 = kt * KVB;
    const float* kb = (kr0 < TXT) ? Kenc : Kimg;
    const int kro = (kr0 < TXT) ? 0 : TXT;
#pragma unroll
    for (int i = 0; i < 9; ++i) {
      const int c = w * 9 + i;                 // wave-uniform chunk id 0..35
      u16* dst = dstbase + c * 512;            // linear 1KB LDS chunk
      const u16* src;
      if (c < 16) {                            // K planes (hi: c<8, lo: 8..15)
        const int plane = c >> 3;
        const int po = (c & 7) * 1024 + lane * 16;   // byte within plane
        const int rowk = po >> 8;
        const int ch = ((po >> 4) & 15) ^ (rowk & 7);  // inverse swizzle on src
        src = (const u16*)(kb + (size_t)(kr0 + rowk - kro) * HID)
              + plane * HID + h * DH + ch * 8;
      } else {                                 // V planes (hi: 16..25, lo: 26..35)
        const int plane = (c >= 26) ? 1 : 0;
        const int t16 = ((c - (plane ? 26 : 16)) * 1024 + lane * 16) >> 4;
        const int dv = (t16 * 52429) >> 18;    // t16/5 (exact for t16<=3276)
        int part = t16 - dv * 5; part = (part > 3) ? 3 : part;  // 5th = pad dup
        src = (plane ? VTl : VTh) + ((size_t)(h * DH + dv)) * SFULL
              + kr0 + part * 8;
      }
      gload16(src, dst);
    }
  };

  stage_issue(0, &Stage[0][0]);
  asm volatile("s_waitcnt vmcnt(0)" ::: "memory");
  __builtin_amdgcn_s_barrier();
  __builtin_amdgcn_sched_barrier(0);

  for (int kt = 0; kt < NKT; ++kt) {
    u16* SB = &Stage[kt & 1][0];
    if (kt + 1 < NKT) stage_issue(kt + 1, &Stage[(kt + 1) & 1][0]);

    // ---- QK^T: S strip 16q x 32k per wave (K read with XOR swizzle)
    f32x4 sA[2] = {(f32x4){0.f, 0.f, 0.f, 0.f}, (f32x4){0.f, 0.f, 0.f, 0.f}};
#pragma unroll
    for (int ks = 0; ks < 4; ++ks)
#pragma unroll
      for (int fn = 0; fn < 2; ++fn) {
        const int krow = fn * 16 + l15;
        const int off = (krow * 256 + ks * 64 + lg * 16) ^ ((krow & 7) << 4);
        bf16x8 kh = *(const bf16x8*)((const char*)SB + off);
        bf16x8 kl = *(const bf16x8*)((const char*)SB + 8192 + off);
        sA[fn] = __builtin_amdgcn_mfma_f32_16x16x32_bf16(qf[ks][0], kh, sA[fn], 0, 0, 0);
        sA[fn] = __builtin_amdgcn_mfma_f32_16x16x32_bf16(qf[ks][1], kh, sA[fn], 0, 0, 0);
        sA[fn] = __builtin_amdgcn_mfma_f32_16x16x32_bf16(qf[ks][0], kl, sA[fn], 0, 0, 0);
      }

    // ---- online softmax, wave-parallel (rows q=lg*4+j, cols k across lanes)
#pragma unroll
    for (int j = 0; j < 4; ++j) {
      float v0 = sA[0][j], v1 = sA[1][j];
      float mx = fmaxf(v0, v1);
      mx = fmaxf(mx, __shfl_xor(mx, 1));
      mx = fmaxf(mx, __shfl_xor(mx, 2));
      mx = fmaxf(mx, __shfl_xor(mx, 4));
      mx = fmaxf(mx, __shfl_xor(mx, 8));
      float mnew = fmaxf(mrun[j], mx);
      float a = __expf(mrun[j] - mnew);
      mrun[j] = mnew;
      float p0 = __expf(v0 - mnew), p1 = __expf(v1 - mnew);
      float ts = p0 + p1;
      ts += __shfl_xor(ts, 1); ts += __shfl_xor(ts, 2);
      ts += __shfl_xor(ts, 4); ts += __shfl_xor(ts, 8);
      lrun[j] = lrun[j] * a + ts;
#pragma unroll
      for (int fn = 0; fn < 8; ++fn) O[fn][j] *= a;
      // P -> hi/lo bf16 into per-wave LDS strip [q][k]
      unsigned hp0 = pkbf(p0, 0.f), hp1 = pkbf(p1, 0.f);
      float lp0 = p0 - __uint_as_float(hp0 << 16);
      float lp1 = p1 - __uint_as_float(hp1 << 16);
      unsigned lo0 = pkbf(lp0, 0.f), lo1 = pkbf(lp1, 0.f);
      const int q = lg * 4 + j;
      Plds[w][0][q * 32 + l15]      = (u16)hp0;
      Plds[w][0][q * 32 + 16 + l15] = (u16)hp1;
      Plds[w][1][q * 32 + l15]      = (u16)lo0;
      Plds[w][1][q * 32 + 16 + l15] = (u16)lo1;
    }

    // ---- P @ V  (A = per-wave P strip, B = VT tile; same-wave LDS dep)
    bf16x8 pa0 = *(const bf16x8*)&Plds[w][0][l15 * 32 + lg * 8];
    bf16x8 pa1 = *(const bf16x8*)&Plds[w][1][l15 * 32 + lg * 8];
    const u16* VhB = SB + 8192;   // u16 offset: Vh plane
    const u16* VlB = SB + 13312;  // Vl plane
#pragma unroll
    for (int fn = 0; fn < 8; ++fn) {
      const int dd = fn * 16 + l15;
      bf16x8 vh = *(const bf16x8*)(VhB + dd * 40 + lg * 8);
      bf16x8 vl = *(const bf16x8*)(VlB + dd * 40 + lg * 8);
      O[fn] = __builtin_amdgcn_mfma_f32_16x16x32_bf16(pa0, vh, O[fn], 0, 0, 0);
      O[fn] = __builtin_amdgcn_mfma_f32_16x16x32_bf16(pa1, vh, O[fn], 0, 0, 0);
      O[fn] = __builtin_amdgcn_mfma_f32_16x16x32_bf16(pa0, vl, O[fn], 0, 0, 0);
    }

    // ---- tile boundary: my next-tile DMAs landed (latency hidden under
    // compute); barrier doubles as "all waves done reading this buffer".
    __builtin_amdgcn_sched_barrier(0);
    asm volatile("s_waitcnt vmcnt(0)" ::: "memory");
    __builtin_amdgcn_s_barrier();
    __builtin_amdgcn_sched_barrier(0);
  }

  // ---- epilogue: normalize, add compact IP output on bbox rows, store fp32
#pragma unroll
  for (int j = 0; j < 4; ++j) {
    const float inv = 1.0f / lrun[j];
    const int s = q0 + w * 16 + lg * 4 + j;
    float* orow = AOUT + (size_t)s * HID + h * DH;
    const float* iprow = nullptr;
    if (s >= TXT) {
      const int t2 = s - TXT, y = t2 >> 5, x = t2 & 31;
      if (y >= 8 && y < 24 && x >= 8 && x < 24)
        iprow = IPOc + (size_t)((y - 8) * 16 + (x - 8)) * HID + h * DH;
    }
#pragma unroll
    for (int fn = 0; fn < 8; ++fn) {
      float val = O[fn][j] * inv;
      const int dd = fn * 16 + l15;
      if (iprow) val += iprow[dd];
      orow[dd] = val;
    }
  }
}

// ---------------------------------------------------------------------------
extern "C" void kernel_launch(void* const* d_in, const int* in_sizes, int n_in,
                              void* d_out, int out_size, void* d_ws, size_t ws_size,
                              hipStream_t stream) {
  const float* x    = (const float*)d_in[0];
  const float* enc  = (const float*)d_in[1];
  const float* ip   = (const float*)d_in[2];
  const float* cosb = (const float*)d_in[3];
  const float* sinb = (const float*)d_in[4];
  const float* Wq   = (const float*)d_in[5];
  const float* bq   = (const float*)d_in[6];
  const float* Wk   = (const float*)d_in[7];
  const float* bk   = (const float*)d_in[8];
  const float* Wv   = (const float*)d_in[9];
  const float* bv   = (const float*)d_in[10];
  const float* nqw  = (const float*)d_in[11];
  const float* nkw  = (const float*)d_in[12];
  const float* Wqa  = (const float*)d_in[13];
  const float* bqa  = (const float*)d_in[14];
  const float* Wka  = (const float*)d_in[15];
  const float* bka  = (const float*)d_in[16];
  const float* Wva  = (const float*)d_in[17];
  const float* bva  = (const float*)d_in[18];
  const float* naqw = (const float*)d_in[19];
  const float* nakw = (const float*)d_in[20];
  const float* Wo   = (const float*)d_in[21];
  const float* bo   = (const float*)d_in[22];
  const float* Wao  = (const float*)d_in[23];
  const float* bao  = (const float*)d_in[24];
  const float* Wkip = (const float*)d_in[25];
  const float* bkip = (const float*)d_in[26];
  const float* Wvip = (const float*)d_in[27];
  const float* bvip = (const float*)d_in[28];
  const float* nipq = (const float*)d_in[29];
  const float* nipk = (const float*)d_in[30];

  float* out_img = (float*)d_out;                       // (1024, 3072)
  float* out_enc = (float*)d_out + (size_t)SIMG * HID;  // (512, 3072)

  float* ws = (float*)d_ws;
  // workspace layout (float offsets), total 19,660,800 floats = 78.6 MB
  float* Qi  = ws + 0;          // img Q fp32 -> packed hi|lo bf16 (1024 rows)
  float* Qe  = ws + 3145728;    // enc Q (512 rows)
  float* Ki  = ws + 4718592;    // img K
  float* Ke  = ws + 7864320;    // enc K
  float* Vi  = ws + 9437184;    // img V  }-> AOUT (1536 rows) after transpose
  float* Ve  = ws + 12582912;   // enc V  }
  float* VTr = ws + 14155776;   // VT region: 4,718,592 floats
  float* IPOc= ws + 18874368;   // compact IP out (256 x 3072)
  // temporaries inside the VT region (dead before v_cvt_transpose runs):
  float* KIP  = VTr;                 // 128x3072
  float* VIP  = VTr + 393216;        // 128x3072
  float* KIPN = VTr + 786432;        // (24,128,128)
  float* VIPN = VTr + 1179648;       // (24,128,128)
  u16* VTh = (u16*)VTr;              // (24,128,1536) hi
  u16* VTl = (u16*)(VTr + 2359296);  // (24,128,1536) lo
  float* AOUT = Vi;                  // rows: 0..511 enc, 512..1535 img

  dim3 blk256(256), blk128(128);

  // 1. QKV projections (img + enc), fused col-segmented MFMA launches
  gemm_seg3<<<dim3(72, 8), blk256, 0, stream>>>(
      x, Seg3{Wq, Wk, Wv, bq, bk, bv, Qi, Ki, Vi}, HID);
  gemm_seg3<<<dim3(72, 4), blk256, 0, stream>>>(
      enc, Seg3{Wqa, Wka, Wva, bqa, bka, bva, Qe, Ke, Ve}, HID);
  // 2. IP K/V projections + normalize/reorder + IP attention (raw fp32 Q)
  gemm_seg3<<<dim3(48, 1), blk256, 0, stream>>>(
      ip, Seg3{Wkip, Wvip, Wvip, bkip, bvip, bvip, KIP, VIP, VIP}, IPD);
  ip_norm_reorder<<<dim3(IPL, NH), blk128, 0, stream>>>(KIP, nipk, KIPN, 1);
  ip_norm_reorder<<<dim3(IPL, NH), blk128, 0, stream>>>(VIP, nullptr, VIPN, 0);
  ip_attn<<<dim3(256, NH), blk128, 0, stream>>>(Qi, KIPN, VIPN, nipq, IPOc);
  // 3. RMS+RoPE+split-bf16 convert in place (Q pre-scaled); V -> VT hi/lo
  rmsrope_cvt<<<dim3(SFULL), dim3(768), 0, stream>>>(Qi, Qe, nqw, naqw, cosb, sinb, ATTN_SCALE);
  rmsrope_cvt<<<dim3(SFULL), dim3(768), 0, stream>>>(Ki, Ke, nkw, nakw, cosb, sinb, 1.0f);
  v_cvt_transpose<<<dim3(24, NH), blk256, 0, stream>>>(Vi, Ve, VTh, VTl);
  // 4. MFMA flash attention (adds compact IP output on bbox rows)
  flash_mfma<<<dim3(24, NH), blk256, 0, stream>>>(Qi, Qe, Ki, Ke, VTh, VTl, IPOc, AOUT);
  // 5. fused output projections (row-segmented: enc rows -> Wao, img -> Wo)
  gemm_out2<<<dim3(24, 12), blk256, 0, stream>>>(
      AOUT, Wao, bao, out_enc, Wo, bo, out_img, HID);
}